// Round 13
// baseline (876.251 us; speedup 1.0000x reference)
//
#include <hip/hip_runtime.h>
#include <hip/hip_bf16.h>

using u16 = unsigned short;
using u32 = unsigned int;

typedef __attribute__((ext_vector_type(8))) short short8;
typedef __attribute__((ext_vector_type(4))) float f32x4;

__device__ __forceinline__ u16 f2bf_u16(float f) {
    __hip_bfloat16 h = __float2bfloat16(f);
    return __builtin_bit_cast(u16, h);
}
__device__ __forceinline__ float bfu(u32 u) { return __uint_as_float(u << 16); }

static constexpr int NN = 50000;
static constexpr int NE = 1600000;
static constexpr int NIDX = 8192;
static constexpr int NRANGE = 8;
static constexpr int RN = NN / NRANGE;
static constexpr int HCH = 16;
static constexpr int NK = NN * NRANGE;
static constexpr int SAB = (NK + 4095) / 4096;
static constexpr int CAPB = 262144;
static constexpr int PEB = 8192;
static constexpr int PGX = (NE + PEB - 1) / PEB;
static constexpr int PSTG = 1536;
static constexpr int ZLB = 64 * 63 / 2;       // 2016 lower-tri z tiles (mult of 8)
static constexpr int ZUB = 64 * 65 / 2;       // 2080 upper-tri z tiles
static constexpr int AGB = NN / 4;            // 12500 node-groups

// ---------------- partition: one edge read -> compacted per-range buckets ----------------

__global__ __launch_bounds__(256)
void partition_kernel(const int* __restrict__ s1, const int* __restrict__ d1,
                      const int* __restrict__ s2, const int* __restrict__ d2,
                      int* __restrict__ bcur, u32* __restrict__ ebuf_d, u16* __restrict__ ebuf_s) {
    __shared__ u32 stage_d[8][PSTG];
    __shared__ u16 stage_s[8][PSTG];
    __shared__ int cnt_d[8], cnt_s[8], base_d[8], base_s[8];
    int enc = blockIdx.y;
    const int* s = enc ? s2 : s1;
    const int* d = enc ? d2 : d1;
    if (threadIdx.x < 8) { cnt_d[threadIdx.x] = 0; cnt_s[threadIdx.x] = 0; }
    __syncthreads();
    int* bc_d = bcur + enc * 16;
    int* bc_s = bcur + enc * 16 + 8;
    u32* bd = ebuf_d + (size_t)enc * 8 * CAPB;
    u16* bs = ebuf_s + (size_t)enc * 8 * CAPB;
    int e0 = blockIdx.x * PEB;
    int e1 = min(e0 + PEB, NE);
    for (int e = e0 + threadIdx.x * 4; e < e1; e += 1024) {
        int4 sv = *(const int4*)(s + e);
        int4 dv = *(const int4*)(d + e);
        #pragma unroll
        for (int j = 0; j < 4; ++j) {
            int src = j == 0 ? sv.x : j == 1 ? sv.y : j == 2 ? sv.z : sv.w;
            int dst = j == 0 ? dv.x : j == 1 ? dv.y : j == 2 ? dv.z : dv.w;
            int rd = dst / RN;
            u32 entry = (u32)src | ((u32)(dst - rd * RN) << 16);
            int slot = atomicAdd(&cnt_d[rd], 1);
            if (slot < PSTG) stage_d[rd][slot] = entry;
            else { int gp = atomicAdd(&bc_d[rd], 1); bd[(size_t)rd * CAPB + gp] = entry; }
            int rs = src / RN;
            int slot2 = atomicAdd(&cnt_s[rs], 1);
            if (slot2 < PSTG) stage_s[rs][slot2] = (u16)(src - rs * RN);
            else { int gp = atomicAdd(&bc_s[rs], 1); bs[(size_t)rs * CAPB + gp] = (u16)(src - rs * RN); }
        }
    }
    __syncthreads();
    if (threadIdx.x < 8) {
        int b = threadIdx.x;
        base_d[b] = atomicAdd(&bc_d[b], min(cnt_d[b], PSTG));
        base_s[b] = atomicAdd(&bc_s[b], min(cnt_s[b], PSTG));
    }
    __syncthreads();
    #pragma unroll
    for (int b = 0; b < 8; ++b) {
        int nb = min(cnt_d[b], PSTG);
        for (int i = threadIdx.x; i < nb; i += 256)
            bd[(size_t)b * CAPB + base_d[b] + i] = stage_d[b][i];
        int ns = min(cnt_s[b], PSTG);
        for (int i = threadIdx.x; i < ns; i += 256)
            bs[(size_t)b * CAPB + base_s[b] + i] = stage_s[b][i];
    }
}

// ---------------- bucket hist ----------------

__global__ __launch_bounds__(256)
void bhist_kernel(const u32* __restrict__ ebuf_d, const u16* __restrict__ ebuf_s,
                  const int* __restrict__ bcur,
                  u32* __restrict__ partial2, u32* __restrict__ partial_out) {
    __shared__ u32 sh[RN * 2];
    int stripe = blockIdx.x & 7, chunk = blockIdx.x >> 3;
    int enc = blockIdx.y & 1, type = blockIdx.y >> 1;
    if (type == 0) {
        for (int i = threadIdx.x; i < RN * 2; i += 256) sh[i] = 0;
        __syncthreads();
        int size = bcur[enc * 16 + stripe];
        int cs = (size + HCH - 1) / HCH;
        int lo = chunk * cs, hi = min(lo + cs, size);
        const u32* b = ebuf_d + ((size_t)enc * 8 + stripe) * CAPB;
        for (int i = lo + threadIdx.x; i < hi; i += 256) {
            u32 e = b[i];
            u32 idx = (e >> 16) * 8 + (e & 0xffffu) / RN;
            atomicAdd(&sh[idx >> 2], 1u << ((idx & 3) * 8));
        }
        __syncthreads();
        u32* p2 = partial2 + ((size_t)enc * HCH + chunk) * (NN * 2) + stripe * (RN * 2);
        for (int i = threadIdx.x; i < RN * 2; i += 256) p2[i] = sh[i];
    } else {
        for (int i = threadIdx.x; i < RN / 2; i += 256) sh[i] = 0;
        __syncthreads();
        int size = bcur[enc * 16 + 8 + stripe];
        int cs = (size + HCH - 1) / HCH;
        int lo = chunk * cs, hi = min(lo + cs, size);
        const u16* b = ebuf_s + ((size_t)enc * 8 + stripe) * CAPB;
        for (int i = lo + threadIdx.x; i < hi; i += 256) {
            u32 sl = b[i];
            atomicAdd(&sh[sl >> 1], 1u << ((sl & 1) * 16));
        }
        __syncthreads();
        u32* po = partial_out + ((size_t)enc * HCH + chunk) * (NN / 2) + stripe * (RN / 2);
        for (int i = threadIdx.x; i < RN / 2; i += 256) po[i] = sh[i];
    }
}

__global__ void reduce_hist_kernel(const u32* __restrict__ partial2,
                                   const u32* __restrict__ partial_out,
                                   int* __restrict__ deg2, float* __restrict__ norms) {
    int i = blockIdx.x * blockDim.x + threadIdx.x;
    if (i >= 2 * NN) return;
    int enc = i / NN;
    int dst = i - enc * NN;
    int cnt[8];
    #pragma unroll
    for (int r = 0; r < 8; ++r) cnt[r] = 0;
    for (int c = 0; c < HCH; ++c) {
        const u32* p = partial2 + ((size_t)enc * HCH + c) * (NN * 2) + dst * 2;
        u32 w0 = p[0], w1 = p[1];
        cnt[0] += w0 & 0xff; cnt[1] += (w0 >> 8) & 0xff; cnt[2] += (w0 >> 16) & 0xff; cnt[3] += w0 >> 24;
        cnt[4] += w1 & 0xff; cnt[5] += (w1 >> 8) & 0xff; cnt[6] += (w1 >> 16) & 0xff; cnt[7] += w1 >> 24;
    }
    int* dp = deg2 + (size_t)enc * NK + dst * 8;
    int din = 0;
    #pragma unroll
    for (int r = 0; r < 8; ++r) { dp[r] = cnt[r]; din += cnt[r]; }
    norms[(enc * 2 + 1) * NN + dst] = rsqrtf(fmaxf((float)din, 1.f));
    int dout = 0;
    for (int c = 0; c < HCH; ++c) {
        u32 w = partial_out[((size_t)enc * HCH + c) * (NN / 2) + (dst >> 1)];
        dout += (w >> ((dst & 1) * 16)) & 0xffff;
    }
    norms[(enc * 2 + 0) * NN + dst] = rsqrtf(fmaxf((float)dout, 1.f));
}

// ---------------- 2-phase scan ----------------

__global__ __launch_bounds__(1024)
void scanA_kernel(const int* __restrict__ deg2, int* __restrict__ rp2_all, int* __restrict__ tot) {
    int enc = blockIdx.y;
    const int* deg = deg2 + (size_t)enc * NK;
    int* rp = rp2_all + (size_t)enc * (NK + 1);
    __shared__ int wsum[16];
    int t = threadIdx.x, lane = t & 63, wid = t >> 6;
    int i0 = blockIdx.x * 4096 + t * 4;
    int4 v = make_int4(0, 0, 0, 0);
    bool in = (i0 + 3 < NK);
    if (in) v = *(const int4*)(deg + i0);
    int s = v.x + v.y + v.z + v.w;
    int x = s;
    #pragma unroll
    for (int d = 1; d < 64; d <<= 1) {
        int y = __shfl_up(x, d, 64);
        if (lane >= d) x += y;
    }
    if (lane == 63) wsum[wid] = x;
    __syncthreads();
    if (t == 0) {
        int run = 0;
        #pragma unroll
        for (int w = 0; w < 16; ++w) { int q = wsum[w]; wsum[w] = run; run += q; }
        tot[enc * SAB + blockIdx.x] = run;
    }
    __syncthreads();
    if (in) {
        int excl = wsum[wid] + x - s;
        rp[i0] = excl;
        rp[i0 + 1] = excl + v.x;
        rp[i0 + 2] = excl + v.x + v.y;
        rp[i0 + 3] = excl + v.x + v.y + v.z;
    }
}

__global__ __launch_bounds__(256)
void scanC_kernel(int* __restrict__ rp2_all, int* __restrict__ cur2_all, const int* __restrict__ tot) {
    int enc = blockIdx.y;
    int* rp = rp2_all + (size_t)enc * (NK + 1);
    int* cur = cur2_all + (size_t)enc * NK;
    int nA = blockIdx.x >> 2;
    int part = 0;
    for (int i = threadIdx.x; i < nA; i += 256) part += tot[enc * SAB + i];
    #pragma unroll
    for (int d = 1; d < 64; d <<= 1) part += __shfl_xor(part, d, 64);
    __shared__ int red[4];
    __shared__ int soff;
    int lane = threadIdx.x & 63, wv = threadIdx.x >> 6;
    if (lane == 0) red[wv] = part;
    __syncthreads();
    if (threadIdx.x == 0) soff = red[0] + red[1] + red[2] + red[3];
    __syncthreads();
    int off = soff;
    int idx = (blockIdx.x * 256 + threadIdx.x) * 4;
    if (idx < NK) {
        int4 v = *(const int4*)(rp + idx);
        v.x += off; v.y += off; v.z += off; v.w += off;
        *(int4*)(rp + idx) = v;
        *(int4*)(cur + idx) = v;
    }
    if (blockIdx.x == 0 && threadIdx.x == 0) rp[NK] = NE;
}

// ---------------- scatter from buckets ----------------

__global__ __launch_bounds__(256)
void scatter_kernel(const u32* __restrict__ ebuf_d, const int* __restrict__ bcur,
                    int* __restrict__ cur2_all, u16* __restrict__ csr_all) {
    int stripe = blockIdx.x & 7, chunk = blockIdx.x >> 3;
    int enc = blockIdx.y;
    int size = bcur[enc * 16 + stripe];
    int cs = (size + 63) / 64;
    int lo = chunk * cs, hi = min(lo + cs, size);
    const u32* b = ebuf_d + ((size_t)enc * 8 + stripe) * CAPB;
    int* cursor = cur2_all + (size_t)enc * NK;
    u16* csr = csr_all + (size_t)enc * NE;
    int base = stripe * RN;
    for (int i = lo + threadIdx.x; i < hi; i += 256) {
        u32 e = b[i];
        int src = e & 0xffff;
        int dst = base + (int)(e >> 16);
        int key = dst * 8 + src / RN;
        int pos = atomicAdd(&cursor[key], 1);
        csr[pos] = (u16)src;
    }
}

__global__ void convw_kernel(const float* __restrict__ W1a, const float* __restrict__ W1b,
                             const float* __restrict__ W2a, const float* __restrict__ W2b,
                             u16* __restrict__ W1t_all, u16* __restrict__ W2t_all) {
    int mat = blockIdx.y;
    int idx = blockIdx.x * blockDim.x + threadIdx.x;
    const float* W; u16* Wt; int K, N;
    if (mat < 2) { W = mat ? W1b : W1a; Wt = W1t_all + (size_t)mat * 512 * 256; K = 512; N = 256; }
    else         { W = (mat == 3) ? W2b : W2a; Wt = W2t_all + (size_t)(mat - 2) * 256 * 128; K = 256; N = 128; }
    if (idx < K * N) {
        int k = idx / N, n = idx - k * N;
        Wt[(size_t)n * K + k] = f2bf_u16(W[idx]);
    }
}

// ---------------- MFMA GEMM: 2-deep pipeline, LDS-repacked epilogue ----------------
// CHIN: A (bf16) is feature-chunked [K/32][NN][32].  COUT: bf16 C chunked [N/32][NN][32].
// Non-TRIANG grid: x=jt (fastest -> A-panel reuse in L2/L3), y=it, z=enc.

template<bool A_F32, bool OUT_BF16, bool TRIANG, bool SCALE, bool CHIN, bool COUT>
__global__ __launch_bounds__(256)
void gemm_kernel(const void* __restrict__ A0_, const void* __restrict__ A1_,
                 const u16* __restrict__ Bt0, const u16* __restrict__ Bt1,
                 void* __restrict__ C0_, void* __restrict__ C1_,
                 const float* __restrict__ rs0, const float* __restrict__ rs1,
                 int M, int N, int K) {
    int enc = blockIdx.z;
    const void* A_ = enc ? A1_ : A0_;
    const u16* Bt = enc ? Bt1 : Bt0;
    void* C_ = enc ? C1_ : C0_;
    const float* rowscale = enc ? rs1 : rs0;

    int it, jt;
    if (TRIANG) {
        int b = blockIdx.x;  // enumerate it<=jt; S(i)=i*(129-i)/2 pairs before row i
        int i = (int)((129.0f - sqrtf(129.f * 129.f - 8.f * b)) * 0.5f);
        while ((i + 1) * (129 - (i + 1)) / 2 <= b) ++i;
        while (i * (129 - i) / 2 > b) --i;
        it = i;
        jt = i + (b - i * (129 - i) / 2);
    } else {
        jt = blockIdx.x; it = blockIdx.y;
    }
    int t = threadIdx.x;
    int brow = it * 128, bcol = jt * 128;
    float* Cf = (float*)C_;
    __shared__ alignas(16) u16 smem[128 * 40 * 2];
    u16* As = smem;
    u16* Bs = smem + 128 * 40;
    int lane = t & 63, wv = t >> 6;
    int wr = wv >> 1, wc = wv & 1;
    f32x4 acc[4][4];
    #pragma unroll
    for (int m = 0; m < 4; ++m)
        #pragma unroll
        for (int n = 0; n < 4; ++n) acc[m][n] = f32x4{0.f, 0.f, 0.f, 0.f};

    float4 a_f0[4], a_f1[4];
    uint4  a_h0[2], a_h1[2];
    uint4  b_h0[2], b_h1[2];

#define LOADT(S, kk) do {                                                          \
    if constexpr (A_F32) {                                                         \
        const float* A = (const float*)A_;                                         \
        _Pragma("unroll")                                                          \
        for (int p = 0; p < 4; ++p) {                                              \
            int r = p * 32 + (t >> 3), c = (t & 7) * 4;                            \
            int gr = brow + r;                                                     \
            a_f##S[p] = make_float4(0.f, 0.f, 0.f, 0.f);                           \
            if (gr < M) a_f##S[p] = *(const float4*)(A + (size_t)gr * K + (kk) + c); \
        }                                                                          \
    } else {                                                                       \
        const u16* A = (const u16*)A_;                                             \
        _Pragma("unroll")                                                          \
        for (int p = 0; p < 2; ++p) {                                              \
            int r = p * 64 + (t >> 2), c = (t & 3) * 8;                            \
            int gr = brow + r;                                                     \
            a_h##S[p] = make_uint4(0u, 0u, 0u, 0u);                                \
            if (gr < M) {                                                          \
                if constexpr (CHIN)                                                \
                    a_h##S[p] = *(const uint4*)(A + (size_t)((kk) >> 5) * NN * 32 + (size_t)gr * 32 + c); \
                else                                                               \
                    a_h##S[p] = *(const uint4*)(A + (size_t)gr * K + (kk) + c);    \
            }                                                                      \
        }                                                                          \
    }                                                                              \
    _Pragma("unroll")                                                              \
    for (int p = 0; p < 2; ++p) {                                                  \
        int r = p * 64 + (t >> 2), c = (t & 3) * 8;                                \
        int gn = bcol + r;                                                         \
        b_h##S[p] = make_uint4(0u, 0u, 0u, 0u);                                    \
        if (gn < N) b_h##S[p] = *(const uint4*)(Bt + (size_t)gn * K + (kk) + c);   \
    }                                                                              \
} while (0)

#define STORET(S) do {                                                             \
    if constexpr (A_F32) {                                                         \
        _Pragma("unroll")                                                          \
        for (int p = 0; p < 4; ++p) {                                              \
            int r = p * 32 + (t >> 3), c = (t & 7) * 4;                            \
            u32 lo = (u32)f2bf_u16(a_f##S[p].x) | ((u32)f2bf_u16(a_f##S[p].y) << 16); \
            u32 hi = (u32)f2bf_u16(a_f##S[p].z) | ((u32)f2bf_u16(a_f##S[p].w) << 16); \
            *(uint2*)&As[r * 40 + c] = make_uint2(lo, hi);                         \
        }                                                                          \
    } else {                                                                       \
        _Pragma("unroll")                                                          \
        for (int p = 0; p < 2; ++p) {                                              \
            int r = p * 64 + (t >> 2), c = (t & 3) * 8;                            \
            *(uint4*)&As[r * 40 + c] = a_h##S[p];                                  \
        }                                                                          \
    }                                                                              \
    _Pragma("unroll")                                                              \
    for (int p = 0; p < 2; ++p) {                                                  \
        int r = p * 64 + (t >> 2), c = (t & 3) * 8;                                \
        *(uint4*)&Bs[r * 40 + c] = b_h##S[p];                                      \
    }                                                                              \
} while (0)

    auto compute = [&]() {
        int kg = (lane >> 4) * 8;
        short8 av[4], bv[4];
        #pragma unroll
        for (int m = 0; m < 4; ++m)
            av[m] = *(const short8*)&As[(wr * 64 + m * 16 + (lane & 15)) * 40 + kg];
        #pragma unroll
        for (int n = 0; n < 4; ++n)
            bv[n] = *(const short8*)&Bs[(wc * 64 + n * 16 + (lane & 15)) * 40 + kg];
        #pragma unroll
        for (int m = 0; m < 4; ++m)
            #pragma unroll
            for (int n = 0; n < 4; ++n)
                acc[m][n] = __builtin_amdgcn_mfma_f32_16x16x32_bf16(av[m], bv[n], acc[m][n], 0, 0, 0);
    };

    LOADT(0, 0);
    LOADT(1, 32);
    for (int k0 = 0; k0 < K; k0 += 64) {
        STORET(0);
        __syncthreads();
        if (k0 + 64 < K) LOADT(0, k0 + 64);
        compute();
        __syncthreads();
        STORET(1);
        __syncthreads();
        if (k0 + 96 < K) LOADT(1, k0 + 96);
        compute();
        __syncthreads();
    }
#undef LOADT
#undef STORET

    const int lane15 = lane & 15, lanehi = lane >> 4;
    if (OUT_BF16) {
        u16* stg = smem + wv * 1024;
        #pragma unroll
        for (int m = 0; m < 4; ++m) {
            #pragma unroll
            for (int n = 0; n < 4; ++n)
                #pragma unroll
                for (int r = 0; r < 4; ++r) {
                    float v = acc[m][n][r];
                    if (SCALE) v *= rowscale[brow + wr * 64 + m * 16 + lanehi * 4 + r];
                    stg[(lanehi * 4 + r) * 64 + n * 16 + lane15] = f2bf_u16(v);
                }
            #pragma unroll
            for (int pass = 0; pass < 2; ++pass) {
                int lr = pass * 8 + (lane >> 3);
                int grow = brow + wr * 64 + m * 16 + lr;
                uint4 w = *(uint4*)&stg[lr * 64 + (lane & 7) * 8];
                if (grow < M) {
                    int col = bcol + wc * 64 + (lane & 7) * 8;
                    u16* dp;
                    if (COUT) dp = (u16*)C_ + (size_t)(col >> 5) * NN * 32 + (size_t)grow * 32 + (col & 31);
                    else      dp = (u16*)C_ + (size_t)grow * N + col;
                    *(uint4*)dp = w;
                }
            }
        }
    } else {
        float* stg = (float*)smem + wv * 1024;
        #pragma unroll
        for (int m = 0; m < 4; ++m) {
            #pragma unroll
            for (int n = 0; n < 4; ++n)
                #pragma unroll
                for (int r = 0; r < 4; ++r) {
                    int row = brow + wr * 64 + m * 16 + lanehi * 4 + r;
                    int col = bcol + wc * 64 + n * 16 + lane15;
                    float v = acc[m][n][r];
                    if (SCALE) v *= rowscale[row];
                    if (TRIANG && col < row) v = 0.f;
                    stg[(lanehi * 4 + r) * 64 + n * 16 + lane15] = v;
                }
            #pragma unroll
            for (int pass = 0; pass < 4; ++pass) {
                int lr = pass * 4 + lanehi;
                int grow = brow + wr * 64 + m * 16 + lr;
                f32x4 w = *(f32x4*)&stg[lr * 64 + lane15 * 4];
                if (grow < M) {
                    float* dp = Cf + (size_t)grow * N + bcol + wc * 64 + lane15 * 4;
                    if (TRIANG) __builtin_nontemporal_store(w, (f32x4*)dp);
                    else *(f32x4*)dp = w;
                }
            }
        }
    }
}

// ---------------- feature-chunked aggregation (single enc) ----------------
// Yc: [NCH][NN][32] bf16 (chunk slice = 3.2 MB -> one XCD's L2; blockIdx%NCH pins chunk->XCD).
// Wave = 1 node; 16 lanes x u32 = 2 features each; 4 edges in flight (lane>>4).
// out: chunked [NCH][NN][32] (bf16 or f32).  ZFILL: first ZLB blocks zero lower-tri z tiles.

template<int NCH, bool RELU, bool OUT_BF16, bool ZFILL>
__global__ __launch_bounds__(256)
void agg_kernel(const u16* __restrict__ Yc, const int* __restrict__ rp2,
                const u16* __restrict__ csr, const float* __restrict__ nd,
                const float* __restrict__ bias, void* __restrict__ out,
                float* __restrict__ zout) {
    int bid = blockIdx.x;
    if (ZFILL) {
        if (bid < ZLB) {
            int b = bid;
            float fit = (sqrtf(8.f * b + 1.f) + 1.f) * 0.5f;
            int it = (int)fit;
            if (it * (it - 1) / 2 > b) --it;
            else if ((it + 1) * it / 2 <= b) ++it;
            int jt = b - it * (it - 1) / 2;
            int brow = it * 128, bcol = jt * 128;
            f32x4 z = {0.f, 0.f, 0.f, 0.f};
            #pragma unroll
            for (int pq = 0; pq < 16; ++pq) {
                int idx = pq * 256 + threadIdx.x;
                int r = idx >> 5, c4 = idx & 31;
                __builtin_nontemporal_store(z, (f32x4*)(zout + (size_t)(brow + r) * NIDX + bcol + c4 * 4));
            }
            return;
        }
        bid -= ZLB;
    }
    int chunk = bid & (NCH - 1);
    int ng = bid >> (NCH == 8 ? 3 : 2);
    int node = ng * 4 + (threadIdx.x >> 6);
    int lane = threadIdx.x & 63;
    int e0 = rp2[node * 8], e1 = rp2[node * 8 + 8];
    const u16* Yb = Yc + (size_t)chunk * NN * 32;
    const int f2 = (lane & 15) * 2;
    const int eo = lane >> 4;
    float a0 = 0.f, a1 = 0.f;

    int e = e0;
    for (; e + 16 <= e1; e += 16) {
        int s0 = csr[e + eo];
        int s1 = csr[e + 4 + eo];
        int s2 = csr[e + 8 + eo];
        int s3 = csr[e + 12 + eo];
        u32 d0 = *(const u32*)(Yb + (size_t)s0 * 32 + f2);
        u32 d1 = *(const u32*)(Yb + (size_t)s1 * 32 + f2);
        u32 d2 = *(const u32*)(Yb + (size_t)s2 * 32 + f2);
        u32 d3 = *(const u32*)(Yb + (size_t)s3 * 32 + f2);
        a0 += bfu(d0 & 0xffffu); a1 += bfu(d0 >> 16);
        a0 += bfu(d1 & 0xffffu); a1 += bfu(d1 >> 16);
        a0 += bfu(d2 & 0xffffu); a1 += bfu(d2 >> 16);
        a0 += bfu(d3 & 0xffffu); a1 += bfu(d3 >> 16);
    }
    for (; e < e1; e += 4) {
        int ei = e + eo;
        if (ei < e1) {
            int s = csr[ei];
            u32 d = *(const u32*)(Yb + (size_t)s * 32 + f2);
            a0 += bfu(d & 0xffffu); a1 += bfu(d >> 16);
        }
    }
    a0 += __shfl_xor(a0, 16, 64); a0 += __shfl_xor(a0, 32, 64);
    a1 += __shfl_xor(a1, 16, 64); a1 += __shfl_xor(a1, 32, 64);
    if (lane < 16) {
        float ndv = nd[node];
        float o0 = a0 * ndv + bias[chunk * 32 + f2];
        float o1 = a1 * ndv + bias[chunk * 32 + f2 + 1];
        if (RELU) { o0 = fmaxf(o0, 0.f); o1 = fmaxf(o1, 0.f); }
        if (OUT_BF16) {
            u32 w = (u32)f2bf_u16(o0) | ((u32)f2bf_u16(o1) << 16);
            *(u32*)((u16*)out + (size_t)chunk * NN * 32 + (size_t)node * 32 + f2) = w;
        } else {
            *(float2*)((float*)out + (size_t)chunk * NN * 32 + (size_t)node * 32 + f2) = make_float2(o0, o1);
        }
    }
}

// ---------------- normalize + build R (H2 is chunked [4][NN][32] f32) ----------------

__global__ __launch_bounds__(256)
void build_r_kernel(const float* __restrict__ H2a, const float* __restrict__ H2b,
                    const int* __restrict__ index, u16* __restrict__ R) {
    int lane = threadIdx.x & 63;
    int row = blockIdx.x * 4 + (threadIdx.x >> 6);
    int g = index[row];
    int ch = lane >> 4;                 // feature f = lane*2 -> chunk = lane>>4
    int off = (lane * 2) & 31;
    float2 a = *(const float2*)(H2a + (size_t)ch * NN * 32 + (size_t)g * 32 + off);
    float2 b = *(const float2*)(H2b + (size_t)ch * NN * 32 + (size_t)g * 32 + off);
    float sa = a.x * a.x + a.y * a.y;
    float sb = b.x * b.x + b.y * b.y;
    #pragma unroll
    for (int d = 1; d < 64; d <<= 1) {
        sa += __shfl_xor(sa, d, 64);
        sb += __shfl_xor(sb, d, 64);
    }
    float inva = 1.f / fmaxf(sqrtf(sa), 1e-12f);
    float invb = 1.f / fmaxf(sqrtf(sb), 1e-12f);
    float ax = a.x * inva, ay = a.y * inva;
    float bx = b.x * invb, by = b.y * invb;
    const float c2 = 0.5f, c3 = 0.28867513459481287f;  // 1/(2*sqrt(3))
    u16* Rp = R + (size_t)row * 256;
    Rp[lane * 2]           = f2bf_u16((ax + bx) * c2);
    Rp[lane * 2 + 1]       = f2bf_u16((ay + by) * c2);
    Rp[128 + lane * 2]     = f2bf_u16((ax - bx) * c3);
    Rp[128 + lane * 2 + 1] = f2bf_u16((ay - by) * c3);
}

// ---------------- launch ----------------

extern "C" void kernel_launch(void* const* d_in, const int* in_sizes, int n_in,
                              void* d_out, int out_size, void* d_ws, size_t ws_size,
                              hipStream_t stream) {
    (void)in_sizes; (void)n_in; (void)out_size; (void)ws_size;
    const float* raw0 = (const float*)d_in[0];
    const float* raw1 = (const float*)d_in[1];
    const int* src1 = (const int*)d_in[2], *dst1 = (const int*)d_in[3];
    const int* src2 = (const int*)d_in[4], *dst2 = (const int*)d_in[5];
    const int* index = (const int*)d_in[6];
    const float* W1a = (const float*)d_in[7];  const float* b1a = (const float*)d_in[8];
    const float* W2a = (const float*)d_in[9];  const float* b2a = (const float*)d_in[10];
    const float* W1b = (const float*)d_in[11]; const float* b1b = (const float*)d_in[12];
    const float* W2b = (const float*)d_in[13]; const float* b2b = (const float*)d_in[14];

    char* wp = (char*)d_ws;
    auto alloc = [&](size_t bytes) -> char* {
        char* r = wp;
        wp += (bytes + 255) & ~(size_t)255;
        return r;
    };
    float* norms   = (float*)alloc((size_t)4 * NN * 4);
    int*   deg2    = (int*)alloc((size_t)2 * NK * 4);
    int*   rp2     = (int*)alloc((size_t)2 * (NK + 1) * 4);
    int*   cur2    = (int*)alloc((size_t)2 * NK * 4);
    int*   tot     = (int*)alloc((size_t)2 * SAB * 4);
    int*   bcur    = (int*)alloc(32 * 4);
    u16*   csr_all = (u16*)alloc((size_t)2 * NE * 2);
    u16*   W1t     = (u16*)alloc((size_t)2 * 512 * 256 * 2);
    u16*   W2t     = (u16*)alloc((size_t)2 * 256 * 128 * 2);
    u16*   Y1      = (u16*)alloc((size_t)2 * NN * 256 * 2);   // chunked [8][NN][32] per enc
    u16*   H1      = (u16*)alloc((size_t)2 * NN * 256 * 2);   // chunked [8][NN][32] per enc
    u16*   Y2      = (u16*)alloc((size_t)2 * NN * 128 * 2);   // chunked [4][NN][32] per enc
    float* H2      = (float*)alloc((size_t)2 * NN * 128 * 4); // chunked [4][NN][32] per enc
    u16*   R       = (u16*)alloc((size_t)NIDX * 256 * 2);
    u32* partial2    = (u32*)Y1;
    u32* partial_out = (u32*)H1;
    u32* ebuf_d      = (u32*)Y2;
    u16* ebuf_s      = (u16*)H2;

    const int MT = (NN + 127) / 128;  // 391 row tiles

    hipMemsetAsync(bcur, 0, 32 * 4, stream);
    convw_kernel<<<dim3((512 * 256 + 255) / 256, 4), 256, 0, stream>>>(W1a, W1b, W2a, W2b, W1t, W2t);
    partition_kernel<<<dim3(PGX, 2), 256, 0, stream>>>(src1, dst1, src2, dst2, bcur, ebuf_d, ebuf_s);
    bhist_kernel<<<dim3(8 * HCH, 4), 256, 0, stream>>>(ebuf_d, ebuf_s, bcur, partial2, partial_out);
    reduce_hist_kernel<<<(2 * NN + 255) / 256, 256, 0, stream>>>(partial2, partial_out, deg2, norms);
    scanA_kernel<<<dim3(SAB, 2), 1024, 0, stream>>>(deg2, rp2, tot);
    scanC_kernel<<<dim3((NK / 4 + 255) / 256, 2), 256, 0, stream>>>(rp2, cur2, tot);
    scatter_kernel<<<dim3(8 * 64, 2), 256, 0, stream>>>(ebuf_d, bcur, cur2, csr_all);

    // Y1c = (raw @ W1) * ns[row]  (jt fastest -> A-panel L2 reuse; chunked output)
    gemm_kernel<true, true, false, true, false, true><<<dim3(2, MT, 2), 256, 0, stream>>>(
        raw0, raw1, W1t, W1t + (size_t)512 * 256, Y1, Y1 + (size_t)NN * 256,
        norms, norms + (size_t)2 * NN, NN, 256, 512);
    // H1c = relu(nd * agg(Y1c) + b1); chunk pinned to XCD (slice L2-resident)
    agg_kernel<8, true, true, true><<<ZLB + 8 * AGB, 256, 0, stream>>>(
        Y1, rp2, csr_all, norms + NN, b1a, H1, (float*)d_out);
    agg_kernel<8, true, true, false><<<8 * AGB, 256, 0, stream>>>(
        Y1 + (size_t)NN * 256, rp2 + (NK + 1), csr_all + (size_t)NE, norms + 3 * NN, b1b,
        H1 + (size_t)NN * 256, nullptr);
    // Y2c = (H1c @ W2) * ns[row]  (chunked A-in and C-out)
    gemm_kernel<false, true, false, true, true, true><<<dim3(1, MT, 2), 256, 0, stream>>>(
        H1, H1 + (size_t)NN * 256, W2t, W2t + (size_t)256 * 128, Y2, Y2 + (size_t)NN * 128,
        norms, norms + (size_t)2 * NN, NN, 128, 256);
    // H2c = nd * agg(Y2c) + b2, f32 chunked
    agg_kernel<4, false, false, false><<<4 * AGB, 256, 0, stream>>>(
        Y2, rp2, csr_all, norms + NN, b2a, H2, nullptr);
    agg_kernel<4, false, false, false><<<4 * AGB, 256, 0, stream>>>(
        Y2 + (size_t)NN * 128, rp2 + (NK + 1), csr_all + (size_t)NE, norms + 3 * NN, b2b,
        H2 + (size_t)NN * 128, nullptr);

    // R = [ (c1n+c2n)/2 , (c1n-c2n)/(2*sqrt(3)) ]  (8192 x 256, bf16 row-major)
    build_r_kernel<<<NIDX / 4, 256, 0, stream>>>(H2, H2 + (size_t)NN * 128, index, R);
    // z = triu(R @ R^T): upper-tri tiles only (lower filled during agg1-enc0)
    gemm_kernel<false, false, true, false, false, false><<<dim3(ZUB, 1, 1), 256, 0, stream>>>(
        R, R, R, R, (float*)d_out, (float*)d_out, nullptr, nullptr, NIDX, NIDX, 256);
}

// Round 14
// 849.593 us; speedup vs baseline: 1.0314x; 1.0314x over previous
//
#include <hip/hip_runtime.h>
#include <hip/hip_bf16.h>

using u16 = unsigned short;
using u32 = unsigned int;

typedef __attribute__((ext_vector_type(8))) short short8;
typedef __attribute__((ext_vector_type(4))) float f32x4;

__device__ __forceinline__ u16 f2bf_u16(float f) {
    __hip_bfloat16 h = __float2bfloat16(f);
    return __builtin_bit_cast(u16, h);
}
__device__ __forceinline__ float bfu(u32 u) { return __uint_as_float(u << 16); }

static constexpr int NN = 50000;
static constexpr int NE = 1600000;
static constexpr int NIDX = 8192;
static constexpr int NRANGE = 8;
static constexpr int RN = NN / NRANGE;
static constexpr int HCH = 16;
static constexpr int NK = NN * NRANGE;
static constexpr int SAB = (NK + 4095) / 4096;
static constexpr int CAPB = 262144;
static constexpr int PEB = 8192;
static constexpr int PGX = (NE + PEB - 1) / PEB;
static constexpr int PSTG = 1536;
static constexpr int ZLB = 64 * 63 / 2;       // 2016 lower-tri z tiles (mult of 8)
static constexpr int ZUB = 64 * 65 / 2;       // 2080 upper-tri z tiles
static constexpr int AGB = NN / 4;            // 12500 node-groups

// ---------------- partition: one edge read -> compacted per-range buckets ----------------

__global__ __launch_bounds__(256)
void partition_kernel(const int* __restrict__ s1, const int* __restrict__ d1,
                      const int* __restrict__ s2, const int* __restrict__ d2,
                      int* __restrict__ bcur, u32* __restrict__ ebuf_d, u16* __restrict__ ebuf_s) {
    __shared__ u32 stage_d[8][PSTG];
    __shared__ u16 stage_s[8][PSTG];
    __shared__ int cnt_d[8], cnt_s[8], base_d[8], base_s[8];
    int enc = blockIdx.y;
    const int* s = enc ? s2 : s1;
    const int* d = enc ? d2 : d1;
    if (threadIdx.x < 8) { cnt_d[threadIdx.x] = 0; cnt_s[threadIdx.x] = 0; }
    __syncthreads();
    int* bc_d = bcur + enc * 16;
    int* bc_s = bcur + enc * 16 + 8;
    u32* bd = ebuf_d + (size_t)enc * 8 * CAPB;
    u16* bs = ebuf_s + (size_t)enc * 8 * CAPB;
    int e0 = blockIdx.x * PEB;
    int e1 = min(e0 + PEB, NE);
    for (int e = e0 + threadIdx.x * 4; e < e1; e += 1024) {
        int4 sv = *(const int4*)(s + e);
        int4 dv = *(const int4*)(d + e);
        #pragma unroll
        for (int j = 0; j < 4; ++j) {
            int src = j == 0 ? sv.x : j == 1 ? sv.y : j == 2 ? sv.z : sv.w;
            int dst = j == 0 ? dv.x : j == 1 ? dv.y : j == 2 ? dv.z : dv.w;
            int rd = dst / RN;
            u32 entry = (u32)src | ((u32)(dst - rd * RN) << 16);
            int slot = atomicAdd(&cnt_d[rd], 1);
            if (slot < PSTG) stage_d[rd][slot] = entry;
            else { int gp = atomicAdd(&bc_d[rd], 1); bd[(size_t)rd * CAPB + gp] = entry; }
            int rs = src / RN;
            int slot2 = atomicAdd(&cnt_s[rs], 1);
            if (slot2 < PSTG) stage_s[rs][slot2] = (u16)(src - rs * RN);
            else { int gp = atomicAdd(&bc_s[rs], 1); bs[(size_t)rs * CAPB + gp] = (u16)(src - rs * RN); }
        }
    }
    __syncthreads();
    if (threadIdx.x < 8) {
        int b = threadIdx.x;
        base_d[b] = atomicAdd(&bc_d[b], min(cnt_d[b], PSTG));
        base_s[b] = atomicAdd(&bc_s[b], min(cnt_s[b], PSTG));
    }
    __syncthreads();
    #pragma unroll
    for (int b = 0; b < 8; ++b) {
        int nb = min(cnt_d[b], PSTG);
        for (int i = threadIdx.x; i < nb; i += 256)
            bd[(size_t)b * CAPB + base_d[b] + i] = stage_d[b][i];
        int ns = min(cnt_s[b], PSTG);
        for (int i = threadIdx.x; i < ns; i += 256)
            bs[(size_t)b * CAPB + base_s[b] + i] = stage_s[b][i];
    }
}

// ---------------- bucket hist ----------------

__global__ __launch_bounds__(256)
void bhist_kernel(const u32* __restrict__ ebuf_d, const u16* __restrict__ ebuf_s,
                  const int* __restrict__ bcur,
                  u32* __restrict__ partial2, u32* __restrict__ partial_out) {
    __shared__ u32 sh[RN * 2];
    int stripe = blockIdx.x & 7, chunk = blockIdx.x >> 3;
    int enc = blockIdx.y & 1, type = blockIdx.y >> 1;
    if (type == 0) {
        for (int i = threadIdx.x; i < RN * 2; i += 256) sh[i] = 0;
        __syncthreads();
        int size = bcur[enc * 16 + stripe];
        int cs = (size + HCH - 1) / HCH;
        int lo = chunk * cs, hi = min(lo + cs, size);
        const u32* b = ebuf_d + ((size_t)enc * 8 + stripe) * CAPB;
        for (int i = lo + threadIdx.x; i < hi; i += 256) {
            u32 e = b[i];
            u32 idx = (e >> 16) * 8 + (e & 0xffffu) / RN;
            atomicAdd(&sh[idx >> 2], 1u << ((idx & 3) * 8));
        }
        __syncthreads();
        u32* p2 = partial2 + ((size_t)enc * HCH + chunk) * (NN * 2) + stripe * (RN * 2);
        for (int i = threadIdx.x; i < RN * 2; i += 256) p2[i] = sh[i];
    } else {
        for (int i = threadIdx.x; i < RN / 2; i += 256) sh[i] = 0;
        __syncthreads();
        int size = bcur[enc * 16 + 8 + stripe];
        int cs = (size + HCH - 1) / HCH;
        int lo = chunk * cs, hi = min(lo + cs, size);
        const u16* b = ebuf_s + ((size_t)enc * 8 + stripe) * CAPB;
        for (int i = lo + threadIdx.x; i < hi; i += 256) {
            u32 sl = b[i];
            atomicAdd(&sh[sl >> 1], 1u << ((sl & 1) * 16));
        }
        __syncthreads();
        u32* po = partial_out + ((size_t)enc * HCH + chunk) * (NN / 2) + stripe * (RN / 2);
        for (int i = threadIdx.x; i < RN / 2; i += 256) po[i] = sh[i];
    }
}

__global__ void reduce_hist_kernel(const u32* __restrict__ partial2,
                                   const u32* __restrict__ partial_out,
                                   int* __restrict__ deg2, float* __restrict__ norms) {
    int i = blockIdx.x * blockDim.x + threadIdx.x;
    if (i >= 2 * NN) return;
    int enc = i / NN;
    int dst = i - enc * NN;
    int cnt[8];
    #pragma unroll
    for (int r = 0; r < 8; ++r) cnt[r] = 0;
    for (int c = 0; c < HCH; ++c) {
        const u32* p = partial2 + ((size_t)enc * HCH + c) * (NN * 2) + dst * 2;
        u32 w0 = p[0], w1 = p[1];
        cnt[0] += w0 & 0xff; cnt[1] += (w0 >> 8) & 0xff; cnt[2] += (w0 >> 16) & 0xff; cnt[3] += w0 >> 24;
        cnt[4] += w1 & 0xff; cnt[5] += (w1 >> 8) & 0xff; cnt[6] += (w1 >> 16) & 0xff; cnt[7] += w1 >> 24;
    }
    int* dp = deg2 + (size_t)enc * NK + dst * 8;
    int din = 0;
    #pragma unroll
    for (int r = 0; r < 8; ++r) { dp[r] = cnt[r]; din += cnt[r]; }
    norms[(enc * 2 + 1) * NN + dst] = rsqrtf(fmaxf((float)din, 1.f));
    int dout = 0;
    for (int c = 0; c < HCH; ++c) {
        u32 w = partial_out[((size_t)enc * HCH + c) * (NN / 2) + (dst >> 1)];
        dout += (w >> ((dst & 1) * 16)) & 0xffff;
    }
    norms[(enc * 2 + 0) * NN + dst] = rsqrtf(fmaxf((float)dout, 1.f));
}

// ---------------- 2-phase scan ----------------

__global__ __launch_bounds__(1024)
void scanA_kernel(const int* __restrict__ deg2, int* __restrict__ rp2_all, int* __restrict__ tot) {
    int enc = blockIdx.y;
    const int* deg = deg2 + (size_t)enc * NK;
    int* rp = rp2_all + (size_t)enc * (NK + 1);
    __shared__ int wsum[16];
    int t = threadIdx.x, lane = t & 63, wid = t >> 6;
    int i0 = blockIdx.x * 4096 + t * 4;
    int4 v = make_int4(0, 0, 0, 0);
    bool in = (i0 + 3 < NK);
    if (in) v = *(const int4*)(deg + i0);
    int s = v.x + v.y + v.z + v.w;
    int x = s;
    #pragma unroll
    for (int d = 1; d < 64; d <<= 1) {
        int y = __shfl_up(x, d, 64);
        if (lane >= d) x += y;
    }
    if (lane == 63) wsum[wid] = x;
    __syncthreads();
    if (t == 0) {
        int run = 0;
        #pragma unroll
        for (int w = 0; w < 16; ++w) { int q = wsum[w]; wsum[w] = run; run += q; }
        tot[enc * SAB + blockIdx.x] = run;
    }
    __syncthreads();
    if (in) {
        int excl = wsum[wid] + x - s;
        rp[i0] = excl;
        rp[i0 + 1] = excl + v.x;
        rp[i0 + 2] = excl + v.x + v.y;
        rp[i0 + 3] = excl + v.x + v.y + v.z;
    }
}

__global__ __launch_bounds__(256)
void scanC_kernel(int* __restrict__ rp2_all, int* __restrict__ cur2_all, const int* __restrict__ tot) {
    int enc = blockIdx.y;
    int* rp = rp2_all + (size_t)enc * (NK + 1);
    int* cur = cur2_all + (size_t)enc * NK;
    int nA = blockIdx.x >> 2;
    int part = 0;
    for (int i = threadIdx.x; i < nA; i += 256) part += tot[enc * SAB + i];
    #pragma unroll
    for (int d = 1; d < 64; d <<= 1) part += __shfl_xor(part, d, 64);
    __shared__ int red[4];
    __shared__ int soff;
    int lane = threadIdx.x & 63, wv = threadIdx.x >> 6;
    if (lane == 0) red[wv] = part;
    __syncthreads();
    if (threadIdx.x == 0) soff = red[0] + red[1] + red[2] + red[3];
    __syncthreads();
    int off = soff;
    int idx = (blockIdx.x * 256 + threadIdx.x) * 4;
    if (idx < NK) {
        int4 v = *(const int4*)(rp + idx);
        v.x += off; v.y += off; v.z += off; v.w += off;
        *(int4*)(rp + idx) = v;
        *(int4*)(cur + idx) = v;
    }
    if (blockIdx.x == 0 && threadIdx.x == 0) rp[NK] = NE;
}

// ---------------- scatter from buckets ----------------

__global__ __launch_bounds__(256)
void scatter_kernel(const u32* __restrict__ ebuf_d, const int* __restrict__ bcur,
                    int* __restrict__ cur2_all, u16* __restrict__ csr_all) {
    int stripe = blockIdx.x & 7, chunk = blockIdx.x >> 3;
    int enc = blockIdx.y;
    int size = bcur[enc * 16 + stripe];
    int cs = (size + 63) / 64;
    int lo = chunk * cs, hi = min(lo + cs, size);
    const u32* b = ebuf_d + ((size_t)enc * 8 + stripe) * CAPB;
    int* cursor = cur2_all + (size_t)enc * NK;
    u16* csr = csr_all + (size_t)enc * NE;
    int base = stripe * RN;
    for (int i = lo + threadIdx.x; i < hi; i += 256) {
        u32 e = b[i];
        int src = e & 0xffff;
        int dst = base + (int)(e >> 16);
        int key = dst * 8 + src / RN;
        int pos = atomicAdd(&cursor[key], 1);
        csr[pos] = (u16)src;
    }
}

__global__ void convw_kernel(const float* __restrict__ W1a, const float* __restrict__ W1b,
                             const float* __restrict__ W2a, const float* __restrict__ W2b,
                             u16* __restrict__ W1t_all, u16* __restrict__ W2t_all) {
    int mat = blockIdx.y;
    int idx = blockIdx.x * blockDim.x + threadIdx.x;
    const float* W; u16* Wt; int K, N;
    if (mat < 2) { W = mat ? W1b : W1a; Wt = W1t_all + (size_t)mat * 512 * 256; K = 512; N = 256; }
    else         { W = (mat == 3) ? W2b : W2a; Wt = W2t_all + (size_t)(mat - 2) * 256 * 128; K = 256; N = 128; }
    if (idx < K * N) {
        int k = idx / N, n = idx - k * N;
        Wt[(size_t)n * K + k] = f2bf_u16(W[idx]);
    }
}

// ---------------- MFMA GEMM: 2-deep pipeline, LDS-repacked epilogue ----------------
// COUT: bf16 C stored feature-chunked [N/32][NN][32].  A always row-major.
// Non-TRIANG grid: x=jt (fastest), y=it, z=enc.  TRIANG: 1D upper-tri grid.

template<bool A_F32, bool OUT_BF16, bool TRIANG, bool SCALE, bool COUT>
__global__ __launch_bounds__(256)
void gemm_kernel(const void* __restrict__ A0_, const void* __restrict__ A1_,
                 const u16* __restrict__ Bt0, const u16* __restrict__ Bt1,
                 void* __restrict__ C0_, void* __restrict__ C1_,
                 const float* __restrict__ rs0, const float* __restrict__ rs1,
                 int M, int N, int K) {
    int enc = blockIdx.z;
    const void* A_ = enc ? A1_ : A0_;
    const u16* Bt = enc ? Bt1 : Bt0;
    void* C_ = enc ? C1_ : C0_;
    const float* rowscale = enc ? rs1 : rs0;

    int it, jt;
    if (TRIANG) {
        int b = blockIdx.x;
        int i = (int)((129.0f - sqrtf(129.f * 129.f - 8.f * b)) * 0.5f);
        while ((i + 1) * (129 - (i + 1)) / 2 <= b) ++i;
        while (i * (129 - i) / 2 > b) --i;
        it = i;
        jt = i + (b - i * (129 - i) / 2);
    } else {
        jt = blockIdx.x; it = blockIdx.y;
    }
    int t = threadIdx.x;
    int brow = it * 128, bcol = jt * 128;
    float* Cf = (float*)C_;
    __shared__ alignas(16) u16 smem[128 * 40 * 2];
    u16* As = smem;
    u16* Bs = smem + 128 * 40;
    int lane = t & 63, wv = t >> 6;
    int wr = wv >> 1, wc = wv & 1;
    f32x4 acc[4][4];
    #pragma unroll
    for (int m = 0; m < 4; ++m)
        #pragma unroll
        for (int n = 0; n < 4; ++n) acc[m][n] = f32x4{0.f, 0.f, 0.f, 0.f};

    float4 a_f0[4], a_f1[4];
    uint4  a_h0[2], a_h1[2];
    uint4  b_h0[2], b_h1[2];

#define LOADT(S, kk) do {                                                          \
    if constexpr (A_F32) {                                                         \
        const float* A = (const float*)A_;                                         \
        _Pragma("unroll")                                                          \
        for (int p = 0; p < 4; ++p) {                                              \
            int r = p * 32 + (t >> 3), c = (t & 7) * 4;                            \
            int gr = brow + r;                                                     \
            a_f##S[p] = make_float4(0.f, 0.f, 0.f, 0.f);                           \
            if (gr < M) a_f##S[p] = *(const float4*)(A + (size_t)gr * K + (kk) + c); \
        }                                                                          \
    } else {                                                                       \
        const u16* A = (const u16*)A_;                                             \
        _Pragma("unroll")                                                          \
        for (int p = 0; p < 2; ++p) {                                              \
            int r = p * 64 + (t >> 2), c = (t & 3) * 8;                            \
            int gr = brow + r;                                                     \
            a_h##S[p] = make_uint4(0u, 0u, 0u, 0u);                                \
            if (gr < M) a_h##S[p] = *(const uint4*)(A + (size_t)gr * K + (kk) + c); \
        }                                                                          \
    }                                                                              \
    _Pragma("unroll")                                                              \
    for (int p = 0; p < 2; ++p) {                                                  \
        int r = p * 64 + (t >> 2), c = (t & 3) * 8;                                \
        int gn = bcol + r;                                                         \
        b_h##S[p] = make_uint4(0u, 0u, 0u, 0u);                                    \
        if (gn < N) b_h##S[p] = *(const uint4*)(Bt + (size_t)gn * K + (kk) + c);   \
    }                                                                              \
} while (0)

#define STORET(S) do {                                                             \
    if constexpr (A_F32) {                                                         \
        _Pragma("unroll")                                                          \
        for (int p = 0; p < 4; ++p) {                                              \
            int r = p * 32 + (t >> 3), c = (t & 7) * 4;                            \
            u32 lo = (u32)f2bf_u16(a_f##S[p].x) | ((u32)f2bf_u16(a_f##S[p].y) << 16); \
            u32 hi = (u32)f2bf_u16(a_f##S[p].z) | ((u32)f2bf_u16(a_f##S[p].w) << 16); \
            *(uint2*)&As[r * 40 + c] = make_uint2(lo, hi);                         \
        }                                                                          \
    } else {                                                                       \
        _Pragma("unroll")                                                          \
        for (int p = 0; p < 2; ++p) {                                              \
            int r = p * 64 + (t >> 2), c = (t & 3) * 8;                            \
            *(uint4*)&As[r * 40 + c] = a_h##S[p];                                  \
        }                                                                          \
    }                                                                              \
    _Pragma("unroll")                                                              \
    for (int p = 0; p < 2; ++p) {                                                  \
        int r = p * 64 + (t >> 2), c = (t & 3) * 8;                                \
        *(uint4*)&Bs[r * 40 + c] = b_h##S[p];                                      \
    }                                                                              \
} while (0)

    auto compute = [&]() {
        int kg = (lane >> 4) * 8;
        short8 av[4], bv[4];
        #pragma unroll
        for (int m = 0; m < 4; ++m)
            av[m] = *(const short8*)&As[(wr * 64 + m * 16 + (lane & 15)) * 40 + kg];
        #pragma unroll
        for (int n = 0; n < 4; ++n)
            bv[n] = *(const short8*)&Bs[(wc * 64 + n * 16 + (lane & 15)) * 40 + kg];
        #pragma unroll
        for (int m = 0; m < 4; ++m)
            #pragma unroll
            for (int n = 0; n < 4; ++n)
                acc[m][n] = __builtin_amdgcn_mfma_f32_16x16x32_bf16(av[m], bv[n], acc[m][n], 0, 0, 0);
    };

    LOADT(0, 0);
    LOADT(1, 32);
    for (int k0 = 0; k0 < K; k0 += 64) {
        STORET(0);
        __syncthreads();
        if (k0 + 64 < K) LOADT(0, k0 + 64);
        compute();
        __syncthreads();
        STORET(1);
        __syncthreads();
        if (k0 + 96 < K) LOADT(1, k0 + 96);
        compute();
        __syncthreads();
    }
#undef LOADT
#undef STORET

    const int lane15 = lane & 15, lanehi = lane >> 4;
    if (OUT_BF16) {
        u16* stg = smem + wv * 1024;
        #pragma unroll
        for (int m = 0; m < 4; ++m) {
            #pragma unroll
            for (int n = 0; n < 4; ++n)
                #pragma unroll
                for (int r = 0; r < 4; ++r) {
                    float v = acc[m][n][r];
                    if (SCALE) v *= rowscale[brow + wr * 64 + m * 16 + lanehi * 4 + r];
                    stg[(lanehi * 4 + r) * 64 + n * 16 + lane15] = f2bf_u16(v);
                }
            #pragma unroll
            for (int pass = 0; pass < 2; ++pass) {
                int lr = pass * 8 + (lane >> 3);
                int grow = brow + wr * 64 + m * 16 + lr;
                uint4 w = *(uint4*)&stg[lr * 64 + (lane & 7) * 8];
                if (grow < M) {
                    int col = bcol + wc * 64 + (lane & 7) * 8;
                    u16* dp;
                    if (COUT) dp = (u16*)C_ + (size_t)(col >> 5) * NN * 32 + (size_t)grow * 32 + (col & 31);
                    else      dp = (u16*)C_ + (size_t)grow * N + col;
                    *(uint4*)dp = w;
                }
            }
        }
    } else {
        float* stg = (float*)smem + wv * 1024;
        #pragma unroll
        for (int m = 0; m < 4; ++m) {
            #pragma unroll
            for (int n = 0; n < 4; ++n)
                #pragma unroll
                for (int r = 0; r < 4; ++r) {
                    int row = brow + wr * 64 + m * 16 + lanehi * 4 + r;
                    int col = bcol + wc * 64 + n * 16 + lane15;
                    float v = acc[m][n][r];
                    if (SCALE) v *= rowscale[row];
                    if (TRIANG && col < row) v = 0.f;
                    stg[(lanehi * 4 + r) * 64 + n * 16 + lane15] = v;
                }
            #pragma unroll
            for (int pass = 0; pass < 4; ++pass) {
                int lr = pass * 4 + lanehi;
                int grow = brow + wr * 64 + m * 16 + lr;
                f32x4 w = *(f32x4*)&stg[lr * 64 + lane15 * 4];
                if (grow < M) {
                    float* dp = Cf + (size_t)grow * N + bcol + wc * 64 + lane15 * 4;
                    if (TRIANG) __builtin_nontemporal_store(w, (f32x4*)dp);
                    else *(f32x4*)dp = w;
                }
            }
        }
    }
}

// ---------------- chunked aggregation (single enc): XCD-L2-resident gather ----------------
// Yc: [NCH][NN][32] bf16; chunk = blockIdx%NCH pins chunk->XCD (slice 3.2 MB < 4 MB L2).
// Wave = 1 node x 1 chunk; 8 lanes/edge-row (uint2 = 4 features), 8 edge-groups,
// x4 unroll -> 4 gathers + 4 idx loads in flight per lane. Output row-major (bf16 or f32).
// ZFILL: first ZLB blocks zero lower-tri z tiles.

template<int NCH, bool RELU, bool OUT_BF16, bool ZFILL>
__global__ __launch_bounds__(256)
void agg_kernel(const u16* __restrict__ Yc, const int* __restrict__ rp2,
                const u16* __restrict__ csr, const float* __restrict__ nd,
                const float* __restrict__ bias, void* __restrict__ out,
                float* __restrict__ zout) {
    int bid = blockIdx.x;
    if (ZFILL) {
        if (bid < ZLB) {
            int b = bid;
            float fit = (sqrtf(8.f * b + 1.f) + 1.f) * 0.5f;
            int it = (int)fit;
            if (it * (it - 1) / 2 > b) --it;
            else if ((it + 1) * it / 2 <= b) ++it;
            int jt = b - it * (it - 1) / 2;
            int brow = it * 128, bcol = jt * 128;
            f32x4 z = {0.f, 0.f, 0.f, 0.f};
            #pragma unroll
            for (int pq = 0; pq < 16; ++pq) {
                int idx = pq * 256 + threadIdx.x;
                int r = idx >> 5, c4 = idx & 31;
                __builtin_nontemporal_store(z, (f32x4*)(zout + (size_t)(brow + r) * NIDX + bcol + c4 * 4));
            }
            return;
        }
        bid -= ZLB;
    }
    constexpr int F = NCH * 32;
    int chunk = bid % NCH;
    int ng = bid / NCH;
    int node = ng * 4 + (threadIdx.x >> 6);
    int lane = threadIdx.x & 63;
    int eg = lane >> 3;        // edge group 0..7
    int fq = lane & 7;         // feature quad within chunk (4 features)
    const u16* Yb = Yc + (size_t)chunk * NN * 32;
    int e0 = rp2[node * 8], e1 = rp2[node * 8 + 8];
    float a0 = 0.f, a1 = 0.f, a2 = 0.f, a3 = 0.f;

    int e = e0;
    for (; e + 32 <= e1; e += 32) {
        int s0 = csr[e + eg];
        int s1 = csr[e + 8 + eg];
        int s2 = csr[e + 16 + eg];
        int s3 = csr[e + 24 + eg];
        uint2 d0 = *(const uint2*)(Yb + (size_t)s0 * 32 + fq * 4);
        uint2 d1 = *(const uint2*)(Yb + (size_t)s1 * 32 + fq * 4);
        uint2 d2 = *(const uint2*)(Yb + (size_t)s2 * 32 + fq * 4);
        uint2 d3 = *(const uint2*)(Yb + (size_t)s3 * 32 + fq * 4);
        a0 += bfu(d0.x & 0xffffu); a1 += bfu(d0.x >> 16); a2 += bfu(d0.y & 0xffffu); a3 += bfu(d0.y >> 16);
        a0 += bfu(d1.x & 0xffffu); a1 += bfu(d1.x >> 16); a2 += bfu(d1.y & 0xffffu); a3 += bfu(d1.y >> 16);
        a0 += bfu(d2.x & 0xffffu); a1 += bfu(d2.x >> 16); a2 += bfu(d2.y & 0xffffu); a3 += bfu(d2.y >> 16);
        a0 += bfu(d3.x & 0xffffu); a1 += bfu(d3.x >> 16); a2 += bfu(d3.y & 0xffffu); a3 += bfu(d3.y >> 16);
    }
    for (; e < e1; e += 8) {
        int ei = e + eg;
        if (ei < e1) {
            int s = csr[ei];
            uint2 d = *(const uint2*)(Yb + (size_t)s * 32 + fq * 4);
            a0 += bfu(d.x & 0xffffu); a1 += bfu(d.x >> 16);
            a2 += bfu(d.y & 0xffffu); a3 += bfu(d.y >> 16);
        }
    }
    // reduce across the 8 edge groups (same fq = lane mod 8)
    a0 += __shfl_xor(a0, 8, 64); a0 += __shfl_xor(a0, 16, 64); a0 += __shfl_xor(a0, 32, 64);
    a1 += __shfl_xor(a1, 8, 64); a1 += __shfl_xor(a1, 16, 64); a1 += __shfl_xor(a1, 32, 64);
    a2 += __shfl_xor(a2, 8, 64); a2 += __shfl_xor(a2, 16, 64); a2 += __shfl_xor(a2, 32, 64);
    a3 += __shfl_xor(a3, 8, 64); a3 += __shfl_xor(a3, 16, 64); a3 += __shfl_xor(a3, 32, 64);
    if (eg == 0) {
        float ndv = nd[node];
        int fb = chunk * 32 + fq * 4;
        float o0 = a0 * ndv + bias[fb];
        float o1 = a1 * ndv + bias[fb + 1];
        float o2 = a2 * ndv + bias[fb + 2];
        float o3 = a3 * ndv + bias[fb + 3];
        if (RELU) {
            o0 = fmaxf(o0, 0.f); o1 = fmaxf(o1, 0.f);
            o2 = fmaxf(o2, 0.f); o3 = fmaxf(o3, 0.f);
        }
        if (OUT_BF16) {
            uint2 w;
            w.x = (u32)f2bf_u16(o0) | ((u32)f2bf_u16(o1) << 16);
            w.y = (u32)f2bf_u16(o2) | ((u32)f2bf_u16(o3) << 16);
            *(uint2*)((u16*)out + (size_t)node * F + fb) = w;
        } else {
            *(float4*)((float*)out + (size_t)node * F + fb) = make_float4(o0, o1, o2, o3);
        }
    }
}

// ---------------- normalize + build R (H2 row-major f32) ----------------

__global__ __launch_bounds__(256)
void build_r_kernel(const float* __restrict__ H2a, const float* __restrict__ H2b,
                    const int* __restrict__ index, u16* __restrict__ R) {
    int lane = threadIdx.x & 63;
    int row = blockIdx.x * 4 + (threadIdx.x >> 6);
    int g = index[row];
    float2 a = *(const float2*)(H2a + (size_t)g * 128 + lane * 2);
    float2 b = *(const float2*)(H2b + (size_t)g * 128 + lane * 2);
    float sa = a.x * a.x + a.y * a.y;
    float sb = b.x * b.x + b.y * b.y;
    #pragma unroll
    for (int d = 1; d < 64; d <<= 1) {
        sa += __shfl_xor(sa, d, 64);
        sb += __shfl_xor(sb, d, 64);
    }
    float inva = 1.f / fmaxf(sqrtf(sa), 1e-12f);
    float invb = 1.f / fmaxf(sqrtf(sb), 1e-12f);
    float ax = a.x * inva, ay = a.y * inva;
    float bx = b.x * invb, by = b.y * invb;
    const float c2 = 0.5f, c3 = 0.28867513459481287f;  // 1/(2*sqrt(3))
    u16* Rp = R + (size_t)row * 256;
    Rp[lane * 2]           = f2bf_u16((ax + bx) * c2);
    Rp[lane * 2 + 1]       = f2bf_u16((ay + by) * c2);
    Rp[128 + lane * 2]     = f2bf_u16((ax - bx) * c3);
    Rp[128 + lane * 2 + 1] = f2bf_u16((ay - by) * c3);
}

// ---------------- launch ----------------

extern "C" void kernel_launch(void* const* d_in, const int* in_sizes, int n_in,
                              void* d_out, int out_size, void* d_ws, size_t ws_size,
                              hipStream_t stream) {
    (void)in_sizes; (void)n_in; (void)out_size; (void)ws_size;
    const float* raw0 = (const float*)d_in[0];
    const float* raw1 = (const float*)d_in[1];
    const int* src1 = (const int*)d_in[2], *dst1 = (const int*)d_in[3];
    const int* src2 = (const int*)d_in[4], *dst2 = (const int*)d_in[5];
    const int* index = (const int*)d_in[6];
    const float* W1a = (const float*)d_in[7];  const float* b1a = (const float*)d_in[8];
    const float* W2a = (const float*)d_in[9];  const float* b2a = (const float*)d_in[10];
    const float* W1b = (const float*)d_in[11]; const float* b1b = (const float*)d_in[12];
    const float* W2b = (const float*)d_in[13]; const float* b2b = (const float*)d_in[14];

    char* wp = (char*)d_ws;
    auto alloc = [&](size_t bytes) -> char* {
        char* r = wp;
        wp += (bytes + 255) & ~(size_t)255;
        return r;
    };
    float* norms   = (float*)alloc((size_t)4 * NN * 4);
    int*   deg2    = (int*)alloc((size_t)2 * NK * 4);
    int*   rp2     = (int*)alloc((size_t)2 * (NK + 1) * 4);
    int*   cur2    = (int*)alloc((size_t)2 * NK * 4);
    int*   tot     = (int*)alloc((size_t)2 * SAB * 4);
    int*   bcur    = (int*)alloc(32 * 4);
    u16*   csr_all = (u16*)alloc((size_t)2 * NE * 2);
    u16*   W1t     = (u16*)alloc((size_t)2 * 512 * 256 * 2);
    u16*   W2t     = (u16*)alloc((size_t)2 * 256 * 128 * 2);
    u16*   Y1      = (u16*)alloc((size_t)2 * NN * 256 * 2);   // chunked [8][NN][32] per enc
    u16*   H1      = (u16*)alloc((size_t)2 * NN * 256 * 2);   // row-major
    u16*   Y2      = (u16*)alloc((size_t)2 * NN * 128 * 2);   // chunked [4][NN][32] per enc
    float* H2      = (float*)alloc((size_t)2 * NN * 128 * 4); // row-major
    u16*   R       = (u16*)alloc((size_t)NIDX * 256 * 2);
    u32* partial2    = (u32*)Y1;
    u32* partial_out = (u32*)H1;
    u32* ebuf_d      = (u32*)Y2;
    u16* ebuf_s      = (u16*)H2;

    const int MT = (NN + 127) / 128;  // 391 row tiles

    hipMemsetAsync(bcur, 0, 32 * 4, stream);
    convw_kernel<<<dim3((512 * 256 + 255) / 256, 4), 256, 0, stream>>>(W1a, W1b, W2a, W2b, W1t, W2t);
    partition_kernel<<<dim3(PGX, 2), 256, 0, stream>>>(src1, dst1, src2, dst2, bcur, ebuf_d, ebuf_s);
    bhist_kernel<<<dim3(8 * HCH, 4), 256, 0, stream>>>(ebuf_d, ebuf_s, bcur, partial2, partial_out);
    reduce_hist_kernel<<<(2 * NN + 255) / 256, 256, 0, stream>>>(partial2, partial_out, deg2, norms);
    scanA_kernel<<<dim3(SAB, 2), 1024, 0, stream>>>(deg2, rp2, tot);
    scanC_kernel<<<dim3((NK / 4 + 255) / 256, 2), 256, 0, stream>>>(rp2, cur2, tot);
    scatter_kernel<<<dim3(8 * 64, 2), 256, 0, stream>>>(ebuf_d, bcur, cur2, csr_all);

    // Y1c = (raw @ W1) * ns[row]  (jt-fastest grid; chunked output)
    gemm_kernel<true, true, false, true, true><<<dim3(2, MT, 2), 256, 0, stream>>>(
        raw0, raw1, W1t, W1t + (size_t)512 * 256, Y1, Y1 + (size_t)NN * 256,
        norms, norms + (size_t)2 * NN, NN, 256, 512);
    // H1 = relu(nd * agg(Y1c) + b1), row-major bf16; per-enc sequential (XCD-L2 slices)
    agg_kernel<8, true, true, true><<<ZLB + 8 * AGB, 256, 0, stream>>>(
        Y1, rp2, csr_all, norms + NN, b1a, H1, (float*)d_out);
    agg_kernel<8, true, true, false><<<8 * AGB, 256, 0, stream>>>(
        Y1 + (size_t)NN * 256, rp2 + (NK + 1), csr_all + (size_t)NE, norms + 3 * NN, b1b,
        H1 + (size_t)NN * 256, nullptr);
    // Y2c = (H1 @ W2) * ns[row]  (row-major A, chunked output)
    gemm_kernel<false, true, false, true, true><<<dim3(1, MT, 2), 256, 0, stream>>>(
        H1, H1 + (size_t)NN * 256, W2t, W2t + (size_t)256 * 128, Y2, Y2 + (size_t)NN * 128,
        norms, norms + (size_t)2 * NN, NN, 128, 256);
    // H2 = nd * agg(Y2c) + b2, row-major f32
    agg_kernel<4, false, false, false><<<4 * AGB, 256, 0, stream>>>(
        Y2, rp2, csr_all, norms + NN, b2a, H2, nullptr);
    agg_kernel<4, false, false, false><<<4 * AGB, 256, 0, stream>>>(
        Y2 + (size_t)NN * 128, rp2 + (NK + 1), csr_all + (size_t)NE, norms + 3 * NN, b2b,
        H2 + (size_t)NN * 128, nullptr);

    // R = [ (c1n+c2n)/2 , (c1n-c2n)/(2*sqrt(3)) ]  (8192 x 256, bf16 row-major)
    build_r_kernel<<<NIDX / 4, 256, 0, stream>>>(H2, H2 + (size_t)NN * 128, index, R);
    // z = triu(R @ R^T): upper-tri tiles only (lower filled during agg1-enc0)
    gemm_kernel<false, false, true, false, false><<<dim3(ZUB, 1, 1), 256, 0, stream>>>(
        R, R, R, R, (float*)d_out, (float*)d_out, nullptr, nullptr, NIDX, NIDX, 256);
}

// Round 15
// 658.927 us; speedup vs baseline: 1.3298x; 1.2894x over previous
//
#include <hip/hip_runtime.h>
#include <hip/hip_bf16.h>

using u16 = unsigned short;
using u32 = unsigned int;

typedef __attribute__((ext_vector_type(8))) short short8;
typedef __attribute__((ext_vector_type(4))) float f32x4;

__device__ __forceinline__ u16 f2bf_u16(float f) {
    __hip_bfloat16 h = __float2bfloat16(f);
    return __builtin_bit_cast(u16, h);
}
__device__ __forceinline__ float bfu(u32 u) { return __uint_as_float(u << 16); }

static constexpr int NN = 50000;
static constexpr int NE = 1600000;
static constexpr int NIDX = 8192;
static constexpr int NRANGE = 8;
static constexpr int RN = NN / NRANGE;
static constexpr int HCH = 16;
static constexpr int NK = NN * NRANGE;
static constexpr int SAB = (NK + 4095) / 4096;
static constexpr int CAPB = 262144;
static constexpr int PEB = 8192;
static constexpr int PGX = (NE + PEB - 1) / PEB;
static constexpr int PSTG = 1536;
static constexpr int ZLB = 64 * 63 / 2;       // 2016 lower-tri z tiles
static constexpr int ZHB = ZLB / 2;           // 1008 fill tiles per enc-row of agg1
static constexpr int ZUB = 64 * 65 / 2;       // 2080 upper-tri z tiles
static constexpr int AGB = NN / 4;            // 12500 node-groups per enc

// ---------------- partition: one edge read -> compacted per-range buckets ----------------

__global__ __launch_bounds__(256)
void partition_kernel(const int* __restrict__ s1, const int* __restrict__ d1,
                      const int* __restrict__ s2, const int* __restrict__ d2,
                      int* __restrict__ bcur, u32* __restrict__ ebuf_d, u16* __restrict__ ebuf_s) {
    __shared__ u32 stage_d[8][PSTG];
    __shared__ u16 stage_s[8][PSTG];
    __shared__ int cnt_d[8], cnt_s[8], base_d[8], base_s[8];
    int enc = blockIdx.y;
    const int* s = enc ? s2 : s1;
    const int* d = enc ? d2 : d1;
    if (threadIdx.x < 8) { cnt_d[threadIdx.x] = 0; cnt_s[threadIdx.x] = 0; }
    __syncthreads();
    int* bc_d = bcur + enc * 16;
    int* bc_s = bcur + enc * 16 + 8;
    u32* bd = ebuf_d + (size_t)enc * 8 * CAPB;
    u16* bs = ebuf_s + (size_t)enc * 8 * CAPB;
    int e0 = blockIdx.x * PEB;
    int e1 = min(e0 + PEB, NE);
    for (int e = e0 + threadIdx.x * 4; e < e1; e += 1024) {
        int4 sv = *(const int4*)(s + e);
        int4 dv = *(const int4*)(d + e);
        #pragma unroll
        for (int j = 0; j < 4; ++j) {
            int src = j == 0 ? sv.x : j == 1 ? sv.y : j == 2 ? sv.z : sv.w;
            int dst = j == 0 ? dv.x : j == 1 ? dv.y : j == 2 ? dv.z : dv.w;
            int rd = dst / RN;
            u32 entry = (u32)src | ((u32)(dst - rd * RN) << 16);
            int slot = atomicAdd(&cnt_d[rd], 1);
            if (slot < PSTG) stage_d[rd][slot] = entry;
            else { int gp = atomicAdd(&bc_d[rd], 1); bd[(size_t)rd * CAPB + gp] = entry; }
            int rs = src / RN;
            int slot2 = atomicAdd(&cnt_s[rs], 1);
            if (slot2 < PSTG) stage_s[rs][slot2] = (u16)(src - rs * RN);
            else { int gp = atomicAdd(&bc_s[rs], 1); bs[(size_t)rs * CAPB + gp] = (u16)(src - rs * RN); }
        }
    }
    __syncthreads();
    if (threadIdx.x < 8) {
        int b = threadIdx.x;
        base_d[b] = atomicAdd(&bc_d[b], min(cnt_d[b], PSTG));
        base_s[b] = atomicAdd(&bc_s[b], min(cnt_s[b], PSTG));
    }
    __syncthreads();
    #pragma unroll
    for (int b = 0; b < 8; ++b) {
        int nb = min(cnt_d[b], PSTG);
        for (int i = threadIdx.x; i < nb; i += 256)
            bd[(size_t)b * CAPB + base_d[b] + i] = stage_d[b][i];
        int ns = min(cnt_s[b], PSTG);
        for (int i = threadIdx.x; i < ns; i += 256)
            bs[(size_t)b * CAPB + base_s[b] + i] = stage_s[b][i];
    }
}

// ---------------- bucket hist ----------------

__global__ __launch_bounds__(256)
void bhist_kernel(const u32* __restrict__ ebuf_d, const u16* __restrict__ ebuf_s,
                  const int* __restrict__ bcur,
                  u32* __restrict__ partial2, u32* __restrict__ partial_out) {
    __shared__ u32 sh[RN * 2];
    int stripe = blockIdx.x & 7, chunk = blockIdx.x >> 3;
    int enc = blockIdx.y & 1, type = blockIdx.y >> 1;
    if (type == 0) {
        for (int i = threadIdx.x; i < RN * 2; i += 256) sh[i] = 0;
        __syncthreads();
        int size = bcur[enc * 16 + stripe];
        int cs = (size + HCH - 1) / HCH;
        int lo = chunk * cs, hi = min(lo + cs, size);
        const u32* b = ebuf_d + ((size_t)enc * 8 + stripe) * CAPB;
        for (int i = lo + threadIdx.x; i < hi; i += 256) {
            u32 e = b[i];
            u32 idx = (e >> 16) * 8 + (e & 0xffffu) / RN;
            atomicAdd(&sh[idx >> 2], 1u << ((idx & 3) * 8));
        }
        __syncthreads();
        u32* p2 = partial2 + ((size_t)enc * HCH + chunk) * (NN * 2) + stripe * (RN * 2);
        for (int i = threadIdx.x; i < RN * 2; i += 256) p2[i] = sh[i];
    } else {
        for (int i = threadIdx.x; i < RN / 2; i += 256) sh[i] = 0;
        __syncthreads();
        int size = bcur[enc * 16 + 8 + stripe];
        int cs = (size + HCH - 1) / HCH;
        int lo = chunk * cs, hi = min(lo + cs, size);
        const u16* b = ebuf_s + ((size_t)enc * 8 + stripe) * CAPB;
        for (int i = lo + threadIdx.x; i < hi; i += 256) {
            u32 sl = b[i];
            atomicAdd(&sh[sl >> 1], 1u << ((sl & 1) * 16));
        }
        __syncthreads();
        u32* po = partial_out + ((size_t)enc * HCH + chunk) * (NN / 2) + stripe * (RN / 2);
        for (int i = threadIdx.x; i < RN / 2; i += 256) po[i] = sh[i];
    }
}

__global__ void reduce_hist_kernel(const u32* __restrict__ partial2,
                                   const u32* __restrict__ partial_out,
                                   int* __restrict__ deg2, float* __restrict__ norms) {
    int i = blockIdx.x * blockDim.x + threadIdx.x;
    if (i >= 2 * NN) return;
    int enc = i / NN;
    int dst = i - enc * NN;
    int cnt[8];
    #pragma unroll
    for (int r = 0; r < 8; ++r) cnt[r] = 0;
    for (int c = 0; c < HCH; ++c) {
        const u32* p = partial2 + ((size_t)enc * HCH + c) * (NN * 2) + dst * 2;
        u32 w0 = p[0], w1 = p[1];
        cnt[0] += w0 & 0xff; cnt[1] += (w0 >> 8) & 0xff; cnt[2] += (w0 >> 16) & 0xff; cnt[3] += w0 >> 24;
        cnt[4] += w1 & 0xff; cnt[5] += (w1 >> 8) & 0xff; cnt[6] += (w1 >> 16) & 0xff; cnt[7] += w1 >> 24;
    }
    int* dp = deg2 + (size_t)enc * NK + dst * 8;
    int din = 0;
    #pragma unroll
    for (int r = 0; r < 8; ++r) { dp[r] = cnt[r]; din += cnt[r]; }
    norms[(enc * 2 + 1) * NN + dst] = rsqrtf(fmaxf((float)din, 1.f));
    int dout = 0;
    for (int c = 0; c < HCH; ++c) {
        u32 w = partial_out[((size_t)enc * HCH + c) * (NN / 2) + (dst >> 1)];
        dout += (w >> ((dst & 1) * 16)) & 0xffff;
    }
    norms[(enc * 2 + 0) * NN + dst] = rsqrtf(fmaxf((float)dout, 1.f));
}

// ---------------- 2-phase scan ----------------

__global__ __launch_bounds__(1024)
void scanA_kernel(const int* __restrict__ deg2, int* __restrict__ rp2_all, int* __restrict__ tot) {
    int enc = blockIdx.y;
    const int* deg = deg2 + (size_t)enc * NK;
    int* rp = rp2_all + (size_t)enc * (NK + 1);
    __shared__ int wsum[16];
    int t = threadIdx.x, lane = t & 63, wid = t >> 6;
    int i0 = blockIdx.x * 4096 + t * 4;
    int4 v = make_int4(0, 0, 0, 0);
    bool in = (i0 + 3 < NK);
    if (in) v = *(const int4*)(deg + i0);
    int s = v.x + v.y + v.z + v.w;
    int x = s;
    #pragma unroll
    for (int d = 1; d < 64; d <<= 1) {
        int y = __shfl_up(x, d, 64);
        if (lane >= d) x += y;
    }
    if (lane == 63) wsum[wid] = x;
    __syncthreads();
    if (t == 0) {
        int run = 0;
        #pragma unroll
        for (int w = 0; w < 16; ++w) { int q = wsum[w]; wsum[w] = run; run += q; }
        tot[enc * SAB + blockIdx.x] = run;
    }
    __syncthreads();
    if (in) {
        int excl = wsum[wid] + x - s;
        rp[i0] = excl;
        rp[i0 + 1] = excl + v.x;
        rp[i0 + 2] = excl + v.x + v.y;
        rp[i0 + 3] = excl + v.x + v.y + v.z;
    }
}

__global__ __launch_bounds__(256)
void scanC_kernel(int* __restrict__ rp2_all, int* __restrict__ cur2_all, const int* __restrict__ tot) {
    int enc = blockIdx.y;
    int* rp = rp2_all + (size_t)enc * (NK + 1);
    int* cur = cur2_all + (size_t)enc * NK;
    int nA = blockIdx.x >> 2;
    int part = 0;
    for (int i = threadIdx.x; i < nA; i += 256) part += tot[enc * SAB + i];
    #pragma unroll
    for (int d = 1; d < 64; d <<= 1) part += __shfl_xor(part, d, 64);
    __shared__ int red[4];
    __shared__ int soff;
    int lane = threadIdx.x & 63, wv = threadIdx.x >> 6;
    if (lane == 0) red[wv] = part;
    __syncthreads();
    if (threadIdx.x == 0) soff = red[0] + red[1] + red[2] + red[3];
    __syncthreads();
    int off = soff;
    int idx = (blockIdx.x * 256 + threadIdx.x) * 4;
    if (idx < NK) {
        int4 v = *(const int4*)(rp + idx);
        v.x += off; v.y += off; v.z += off; v.w += off;
        *(int4*)(rp + idx) = v;
        *(int4*)(cur + idx) = v;
    }
    if (blockIdx.x == 0 && threadIdx.x == 0) rp[NK] = NE;
}

// ---------------- scatter from buckets ----------------

__global__ __launch_bounds__(256)
void scatter_kernel(const u32* __restrict__ ebuf_d, const int* __restrict__ bcur,
                    int* __restrict__ cur2_all, u16* __restrict__ csr_all) {
    int stripe = blockIdx.x & 7, chunk = blockIdx.x >> 3;
    int enc = blockIdx.y;
    int size = bcur[enc * 16 + stripe];
    int cs = (size + 63) / 64;
    int lo = chunk * cs, hi = min(lo + cs, size);
    const u32* b = ebuf_d + ((size_t)enc * 8 + stripe) * CAPB;
    int* cursor = cur2_all + (size_t)enc * NK;
    u16* csr = csr_all + (size_t)enc * NE;
    int base = stripe * RN;
    for (int i = lo + threadIdx.x; i < hi; i += 256) {
        u32 e = b[i];
        int src = e & 0xffff;
        int dst = base + (int)(e >> 16);
        int key = dst * 8 + src / RN;
        int pos = atomicAdd(&cursor[key], 1);
        csr[pos] = (u16)src;
    }
}

__global__ void convw_kernel(const float* __restrict__ W1a, const float* __restrict__ W1b,
                             const float* __restrict__ W2a, const float* __restrict__ W2b,
                             u16* __restrict__ W1t_all, u16* __restrict__ W2t_all) {
    int mat = blockIdx.y;
    int idx = blockIdx.x * blockDim.x + threadIdx.x;
    const float* W; u16* Wt; int K, N;
    if (mat < 2) { W = mat ? W1b : W1a; Wt = W1t_all + (size_t)mat * 512 * 256; K = 512; N = 256; }
    else         { W = (mat == 3) ? W2b : W2a; Wt = W2t_all + (size_t)(mat - 2) * 256 * 128; K = 256; N = 128; }
    if (idx < K * N) {
        int k = idx / N, n = idx - k * N;
        Wt[(size_t)n * K + k] = f2bf_u16(W[idx]);
    }
}

// ---------------- MFMA GEMM: 2-deep pipeline, LDS-repacked epilogue ----------------
// Row-major A and C.  TRIANG: 1D upper-tri grid (it<=jt), NT stores.

template<bool A_F32, bool OUT_BF16, bool TRIANG, bool SCALE>
__global__ __launch_bounds__(256)
void gemm_kernel(const void* __restrict__ A0_, const void* __restrict__ A1_,
                 const u16* __restrict__ Bt0, const u16* __restrict__ Bt1,
                 void* __restrict__ C0_, void* __restrict__ C1_,
                 const float* __restrict__ rs0, const float* __restrict__ rs1,
                 int M, int N, int K) {
    int enc = blockIdx.z;
    const void* A_ = enc ? A1_ : A0_;
    const u16* Bt = enc ? Bt1 : Bt0;
    void* C_ = enc ? C1_ : C0_;
    const float* rowscale = enc ? rs1 : rs0;

    int it, jt;
    if (TRIANG) {
        int b = blockIdx.x;
        int i = (int)((129.0f - sqrtf(129.f * 129.f - 8.f * b)) * 0.5f);
        while ((i + 1) * (129 - (i + 1)) / 2 <= b) ++i;
        while (i * (129 - i) / 2 > b) --i;
        it = i;
        jt = i + (b - i * (129 - i) / 2);
    } else {
        it = blockIdx.x; jt = blockIdx.y;
    }
    int t = threadIdx.x;
    int brow = it * 128, bcol = jt * 128;
    float* Cf = (float*)C_;
    __shared__ alignas(16) u16 smem[128 * 40 * 2];
    u16* As = smem;
    u16* Bs = smem + 128 * 40;
    int lane = t & 63, wv = t >> 6;
    int wr = wv >> 1, wc = wv & 1;
    f32x4 acc[4][4];
    #pragma unroll
    for (int m = 0; m < 4; ++m)
        #pragma unroll
        for (int n = 0; n < 4; ++n) acc[m][n] = f32x4{0.f, 0.f, 0.f, 0.f};

    float4 a_f0[4], a_f1[4];
    uint4  a_h0[2], a_h1[2];
    uint4  b_h0[2], b_h1[2];

#define LOADT(S, kk) do {                                                          \
    if constexpr (A_F32) {                                                         \
        const float* A = (const float*)A_;                                         \
        _Pragma("unroll")                                                          \
        for (int p = 0; p < 4; ++p) {                                              \
            int r = p * 32 + (t >> 3), c = (t & 7) * 4;                            \
            int gr = brow + r;                                                     \
            a_f##S[p] = make_float4(0.f, 0.f, 0.f, 0.f);                           \
            if (gr < M) a_f##S[p] = *(const float4*)(A + (size_t)gr * K + (kk) + c); \
        }                                                                          \
    } else {                                                                       \
        const u16* A = (const u16*)A_;                                             \
        _Pragma("unroll")                                                          \
        for (int p = 0; p < 2; ++p) {                                              \
            int r = p * 64 + (t >> 2), c = (t & 3) * 8;                            \
            int gr = brow + r;                                                     \
            a_h##S[p] = make_uint4(0u, 0u, 0u, 0u);                                \
            if (gr < M) a_h##S[p] = *(const uint4*)(A + (size_t)gr * K + (kk) + c); \
        }                                                                          \
    }                                                                              \
    _Pragma("unroll")                                                              \
    for (int p = 0; p < 2; ++p) {                                                  \
        int r = p * 64 + (t >> 2), c = (t & 3) * 8;                                \
        int gn = bcol + r;                                                         \
        b_h##S[p] = make_uint4(0u, 0u, 0u, 0u);                                    \
        if (gn < N) b_h##S[p] = *(const uint4*)(Bt + (size_t)gn * K + (kk) + c);   \
    }                                                                              \
} while (0)

#define STORET(S) do {                                                             \
    if constexpr (A_F32) {                                                         \
        _Pragma("unroll")                                                          \
        for (int p = 0; p < 4; ++p) {                                              \
            int r = p * 32 + (t >> 3), c = (t & 7) * 4;                            \
            u32 lo = (u32)f2bf_u16(a_f##S[p].x) | ((u32)f2bf_u16(a_f##S[p].y) << 16); \
            u32 hi = (u32)f2bf_u16(a_f##S[p].z) | ((u32)f2bf_u16(a_f##S[p].w) << 16); \
            *(uint2*)&As[r * 40 + c] = make_uint2(lo, hi);                         \
        }                                                                          \
    } else {                                                                       \
        _Pragma("unroll")                                                          \
        for (int p = 0; p < 2; ++p) {                                              \
            int r = p * 64 + (t >> 2), c = (t & 3) * 8;                            \
            *(uint4*)&As[r * 40 + c] = a_h##S[p];                                  \
        }                                                                          \
    }                                                                              \
    _Pragma("unroll")                                                              \
    for (int p = 0; p < 2; ++p) {                                                  \
        int r = p * 64 + (t >> 2), c = (t & 3) * 8;                                \
        *(uint4*)&Bs[r * 40 + c] = b_h##S[p];                                      \
    }                                                                              \
} while (0)

    auto compute = [&]() {
        int kg = (lane >> 4) * 8;
        short8 av[4], bv[4];
        #pragma unroll
        for (int m = 0; m < 4; ++m)
            av[m] = *(const short8*)&As[(wr * 64 + m * 16 + (lane & 15)) * 40 + kg];
        #pragma unroll
        for (int n = 0; n < 4; ++n)
            bv[n] = *(const short8*)&Bs[(wc * 64 + n * 16 + (lane & 15)) * 40 + kg];
        #pragma unroll
        for (int m = 0; m < 4; ++m)
            #pragma unroll
            for (int n = 0; n < 4; ++n)
                acc[m][n] = __builtin_amdgcn_mfma_f32_16x16x32_bf16(av[m], bv[n], acc[m][n], 0, 0, 0);
    };

    LOADT(0, 0);
    LOADT(1, 32);
    for (int k0 = 0; k0 < K; k0 += 64) {
        STORET(0);
        __syncthreads();
        if (k0 + 64 < K) LOADT(0, k0 + 64);
        compute();
        __syncthreads();
        STORET(1);
        __syncthreads();
        if (k0 + 96 < K) LOADT(1, k0 + 96);
        compute();
        __syncthreads();
    }
#undef LOADT
#undef STORET

    const int lane15 = lane & 15, lanehi = lane >> 4;
    if (OUT_BF16) {
        u16* stg = smem + wv * 1024;
        #pragma unroll
        for (int m = 0; m < 4; ++m) {
            #pragma unroll
            for (int n = 0; n < 4; ++n)
                #pragma unroll
                for (int r = 0; r < 4; ++r) {
                    float v = acc[m][n][r];
                    if (SCALE) v *= rowscale[brow + wr * 64 + m * 16 + lanehi * 4 + r];
                    stg[(lanehi * 4 + r) * 64 + n * 16 + lane15] = f2bf_u16(v);
                }
            #pragma unroll
            for (int pass = 0; pass < 2; ++pass) {
                int lr = pass * 8 + (lane >> 3);
                int grow = brow + wr * 64 + m * 16 + lr;
                uint4 w = *(uint4*)&stg[lr * 64 + (lane & 7) * 8];
                if (grow < M)
                    *(uint4*)((u16*)C_ + (size_t)grow * N + bcol + wc * 64 + (lane & 7) * 8) = w;
            }
        }
    } else {
        float* stg = (float*)smem + wv * 1024;
        #pragma unroll
        for (int m = 0; m < 4; ++m) {
            #pragma unroll
            for (int n = 0; n < 4; ++n)
                #pragma unroll
                for (int r = 0; r < 4; ++r) {
                    int row = brow + wr * 64 + m * 16 + lanehi * 4 + r;
                    int col = bcol + wc * 64 + n * 16 + lane15;
                    float v = acc[m][n][r];
                    if (SCALE) v *= rowscale[row];
                    if (TRIANG && col < row) v = 0.f;
                    stg[(lanehi * 4 + r) * 64 + n * 16 + lane15] = v;
                }
            #pragma unroll
            for (int pass = 0; pass < 4; ++pass) {
                int lr = pass * 4 + lanehi;
                int grow = brow + wr * 64 + m * 16 + lr;
                f32x4 w = *(f32x4*)&stg[lr * 64 + lane15 * 4];
                if (grow < M) {
                    float* dp = Cf + (size_t)grow * N + bcol + wc * 64 + lane15 * 4;
                    if (TRIANG) __builtin_nontemporal_store(w, (f32x4*)dp);
                    else *(f32x4*)dp = w;
                }
            }
        }
    }
}

// ---------------- row-major aggregation, dual-enc (grid.y = enc) ----------------
// out[node] = nd[node]*sum Y[csr[e]] + b (Y pre-scaled by ns in GEMM epilogue).
// 16-edge unroll (F=256): 2x uint4 index loads + 16 uint2 gathers in flight.
// ZFILL: first ZHB blocks of each enc-row zero half the lower-tri z tiles.

template<int F, bool RELU, bool OUT_BF16, bool ZFILL>
__global__ __launch_bounds__(256)
void agg_kernel(const u16* __restrict__ Yall, const int* __restrict__ rp2_all,
                const u16* __restrict__ csr_all, const float* __restrict__ norms,
                const float* __restrict__ bias0, const float* __restrict__ bias1,
                void* __restrict__ out_all, float* __restrict__ zout) {
    constexpr int VPL = F / 64;
    int enc = blockIdx.y;
    int bid = blockIdx.x;
    if (ZFILL) {
        if (bid < ZHB) {
            int b = enc * ZHB + bid;
            float fit = (sqrtf(8.f * b + 1.f) + 1.f) * 0.5f;
            int it = (int)fit;
            if (it * (it - 1) / 2 > b) --it;
            else if ((it + 1) * it / 2 <= b) ++it;
            int jt = b - it * (it - 1) / 2;
            int brow = it * 128, bcol = jt * 128;
            f32x4 z = {0.f, 0.f, 0.f, 0.f};
            #pragma unroll
            for (int pq = 0; pq < 16; ++pq) {
                int idx = pq * 256 + threadIdx.x;
                int r = idx >> 5, c4 = idx & 31;
                __builtin_nontemporal_store(z, (f32x4*)(zout + (size_t)(brow + r) * NIDX + bcol + c4 * 4));
            }
            return;
        }
        bid -= ZHB;
    }
    const u16* Y = Yall + (size_t)enc * NN * F;
    const int* rp2 = rp2_all + (size_t)enc * (NK + 1);
    const u16* csr = csr_all + (size_t)enc * NE;
    const float* nd = norms + (size_t)(2 * enc + 1) * NN;
    const float* bias = enc ? bias1 : bias0;
    int lane = threadIdx.x & 63;
    int node = bid * 4 + (threadIdx.x >> 6);
    int e0 = rp2[node * 8], e1 = rp2[node * 8 + 8];
    float acc[VPL];
    #pragma unroll
    for (int j = 0; j < VPL; ++j) acc[j] = 0.f;
    const int off = lane * VPL;

    int e = e0;
    for (; e < e1 && (e & 7) != 0; ++e) {
        int s = csr[e];
        if (VPL == 4) {
            uint2 d = *(const uint2*)(Y + (size_t)s * F + off);
            acc[0] += bfu(d.x & 0xffffu); acc[1] += bfu(d.x >> 16);
            acc[2] += bfu(d.y & 0xffffu); acc[3] += bfu(d.y >> 16);
        } else {
            u32 d = *(const u32*)(Y + (size_t)s * F + off);
            acc[0] += bfu(d & 0xffffu); acc[1] += bfu(d >> 16);
        }
    }
    if (VPL == 4) {
        for (; e + 16 <= e1; e += 16) {
            uint4 ia = *(const uint4*)(csr + e);
            uint4 ib = *(const uint4*)(csr + e + 8);
            int s0 = ia.x & 0xffff, s1 = ia.x >> 16, s2 = ia.y & 0xffff, s3 = ia.y >> 16;
            int s4 = ia.z & 0xffff, s5 = ia.z >> 16, s6 = ia.w & 0xffff, s7 = ia.w >> 16;
            int s8 = ib.x & 0xffff, s9 = ib.x >> 16, sa = ib.y & 0xffff, sb = ib.y >> 16;
            int sc = ib.z & 0xffff, sd = ib.z >> 16, se = ib.w & 0xffff, sf = ib.w >> 16;
            uint2 d0 = *(const uint2*)(Y + (size_t)s0 * F + off);
            uint2 d1 = *(const uint2*)(Y + (size_t)s1 * F + off);
            uint2 d2 = *(const uint2*)(Y + (size_t)s2 * F + off);
            uint2 d3 = *(const uint2*)(Y + (size_t)s3 * F + off);
            uint2 d4 = *(const uint2*)(Y + (size_t)s4 * F + off);
            uint2 d5 = *(const uint2*)(Y + (size_t)s5 * F + off);
            uint2 d6 = *(const uint2*)(Y + (size_t)s6 * F + off);
            uint2 d7 = *(const uint2*)(Y + (size_t)s7 * F + off);
            uint2 d8 = *(const uint2*)(Y + (size_t)s8 * F + off);
            uint2 d9 = *(const uint2*)(Y + (size_t)s9 * F + off);
            uint2 da = *(const uint2*)(Y + (size_t)sa * F + off);
            uint2 db = *(const uint2*)(Y + (size_t)sb * F + off);
            uint2 dc = *(const uint2*)(Y + (size_t)sc * F + off);
            uint2 dd = *(const uint2*)(Y + (size_t)sd * F + off);
            uint2 de = *(const uint2*)(Y + (size_t)se * F + off);
            uint2 df = *(const uint2*)(Y + (size_t)sf * F + off);
            acc[0] += bfu(d0.x & 0xffffu); acc[1] += bfu(d0.x >> 16); acc[2] += bfu(d0.y & 0xffffu); acc[3] += bfu(d0.y >> 16);
            acc[0] += bfu(d1.x & 0xffffu); acc[1] += bfu(d1.x >> 16); acc[2] += bfu(d1.y & 0xffffu); acc[3] += bfu(d1.y >> 16);
            acc[0] += bfu(d2.x & 0xffffu); acc[1] += bfu(d2.x >> 16); acc[2] += bfu(d2.y & 0xffffu); acc[3] += bfu(d2.y >> 16);
            acc[0] += bfu(d3.x & 0xffffu); acc[1] += bfu(d3.x >> 16); acc[2] += bfu(d3.y & 0xffffu); acc[3] += bfu(d3.y >> 16);
            acc[0] += bfu(d4.x & 0xffffu); acc[1] += bfu(d4.x >> 16); acc[2] += bfu(d4.y & 0xffffu); acc[3] += bfu(d4.y >> 16);
            acc[0] += bfu(d5.x & 0xffffu); acc[1] += bfu(d5.x >> 16); acc[2] += bfu(d5.y & 0xffffu); acc[3] += bfu(d5.y >> 16);
            acc[0] += bfu(d6.x & 0xffffu); acc[1] += bfu(d6.x >> 16); acc[2] += bfu(d6.y & 0xffffu); acc[3] += bfu(d6.y >> 16);
            acc[0] += bfu(d7.x & 0xffffu); acc[1] += bfu(d7.x >> 16); acc[2] += bfu(d7.y & 0xffffu); acc[3] += bfu(d7.y >> 16);
            acc[0] += bfu(d8.x & 0xffffu); acc[1] += bfu(d8.x >> 16); acc[2] += bfu(d8.y & 0xffffu); acc[3] += bfu(d8.y >> 16);
            acc[0] += bfu(d9.x & 0xffffu); acc[1] += bfu(d9.x >> 16); acc[2] += bfu(d9.y & 0xffffu); acc[3] += bfu(d9.y >> 16);
            acc[0] += bfu(da.x & 0xffffu); acc[1] += bfu(da.x >> 16); acc[2] += bfu(da.y & 0xffffu); acc[3] += bfu(da.y >> 16);
            acc[0] += bfu(db.x & 0xffffu); acc[1] += bfu(db.x >> 16); acc[2] += bfu(db.y & 0xffffu); acc[3] += bfu(db.y >> 16);
            acc[0] += bfu(dc.x & 0xffffu); acc[1] += bfu(dc.x >> 16); acc[2] += bfu(dc.y & 0xffffu); acc[3] += bfu(dc.y >> 16);
            acc[0] += bfu(dd.x & 0xffffu); acc[1] += bfu(dd.x >> 16); acc[2] += bfu(dd.y & 0xffffu); acc[3] += bfu(dd.y >> 16);
            acc[0] += bfu(de.x & 0xffffu); acc[1] += bfu(de.x >> 16); acc[2] += bfu(de.y & 0xffffu); acc[3] += bfu(de.y >> 16);
            acc[0] += bfu(df.x & 0xffffu); acc[1] += bfu(df.x >> 16); acc[2] += bfu(df.y & 0xffffu); acc[3] += bfu(df.y >> 16);
        }
    }
    for (; e + 8 <= e1; e += 8) {
        uint4 iv = *(const uint4*)(csr + e);
        int s0 = iv.x & 0xffff, s1 = iv.x >> 16;
        int s2 = iv.y & 0xffff, s3 = iv.y >> 16;
        int s4 = iv.z & 0xffff, s5 = iv.z >> 16;
        int s6 = iv.w & 0xffff, s7 = iv.w >> 16;
        if (VPL == 4) {
            uint2 d0 = *(const uint2*)(Y + (size_t)s0 * F + off);
            uint2 d1 = *(const uint2*)(Y + (size_t)s1 * F + off);
            uint2 d2 = *(const uint2*)(Y + (size_t)s2 * F + off);
            uint2 d3 = *(const uint2*)(Y + (size_t)s3 * F + off);
            uint2 d4 = *(const uint2*)(Y + (size_t)s4 * F + off);
            uint2 d5 = *(const uint2*)(Y + (size_t)s5 * F + off);
            uint2 d6 = *(const uint2*)(Y + (size_t)s6 * F + off);
            uint2 d7 = *(const uint2*)(Y + (size_t)s7 * F + off);
            acc[0] += bfu(d0.x & 0xffffu); acc[1] += bfu(d0.x >> 16); acc[2] += bfu(d0.y & 0xffffu); acc[3] += bfu(d0.y >> 16);
            acc[0] += bfu(d1.x & 0xffffu); acc[1] += bfu(d1.x >> 16); acc[2] += bfu(d1.y & 0xffffu); acc[3] += bfu(d1.y >> 16);
            acc[0] += bfu(d2.x & 0xffffu); acc[1] += bfu(d2.x >> 16); acc[2] += bfu(d2.y & 0xffffu); acc[3] += bfu(d2.y >> 16);
            acc[0] += bfu(d3.x & 0xffffu); acc[1] += bfu(d3.x >> 16); acc[2] += bfu(d3.y & 0xffffu); acc[3] += bfu(d3.y >> 16);
            acc[0] += bfu(d4.x & 0xffffu); acc[1] += bfu(d4.x >> 16); acc[2] += bfu(d4.y & 0xffffu); acc[3] += bfu(d4.y >> 16);
            acc[0] += bfu(d5.x & 0xffffu); acc[1] += bfu(d5.x >> 16); acc[2] += bfu(d5.y & 0xffffu); acc[3] += bfu(d5.y >> 16);
            acc[0] += bfu(d6.x & 0xffffu); acc[1] += bfu(d6.x >> 16); acc[2] += bfu(d6.y & 0xffffu); acc[3] += bfu(d6.y >> 16);
            acc[0] += bfu(d7.x & 0xffffu); acc[1] += bfu(d7.x >> 16); acc[2] += bfu(d7.y & 0xffffu); acc[3] += bfu(d7.y >> 16);
        } else {
            u32 d0 = *(const u32*)(Y + (size_t)s0 * F + off);
            u32 d1 = *(const u32*)(Y + (size_t)s1 * F + off);
            u32 d2 = *(const u32*)(Y + (size_t)s2 * F + off);
            u32 d3 = *(const u32*)(Y + (size_t)s3 * F + off);
            u32 d4 = *(const u32*)(Y + (size_t)s4 * F + off);
            u32 d5 = *(const u32*)(Y + (size_t)s5 * F + off);
            u32 d6 = *(const u32*)(Y + (size_t)s6 * F + off);
            u32 d7 = *(const u32*)(Y + (size_t)s7 * F + off);
            acc[0] += bfu(d0 & 0xffffu); acc[1] += bfu(d0 >> 16);
            acc[0] += bfu(d1 & 0xffffu); acc[1] += bfu(d1 >> 16);
            acc[0] += bfu(d2 & 0xffffu); acc[1] += bfu(d2 >> 16);
            acc[0] += bfu(d3 & 0xffffu); acc[1] += bfu(d3 >> 16);
            acc[0] += bfu(d4 & 0xffffu); acc[1] += bfu(d4 >> 16);
            acc[0] += bfu(d5 & 0xffffu); acc[1] += bfu(d5 >> 16);
            acc[0] += bfu(d6 & 0xffffu); acc[1] += bfu(d6 >> 16);
            acc[0] += bfu(d7 & 0xffffu); acc[1] += bfu(d7 >> 16);
        }
    }
    for (; e < e1; ++e) {
        int s = csr[e];
        if (VPL == 4) {
            uint2 d = *(const uint2*)(Y + (size_t)s * F + off);
            acc[0] += bfu(d.x & 0xffffu); acc[1] += bfu(d.x >> 16);
            acc[2] += bfu(d.y & 0xffffu); acc[3] += bfu(d.y >> 16);
        } else {
            u32 d = *(const u32*)(Y + (size_t)s * F + off);
            acc[0] += bfu(d & 0xffffu); acc[1] += bfu(d >> 16);
        }
    }

    float ndv = nd[node];
    #pragma unroll
    for (int j = 0; j < VPL; ++j) {
        float o = acc[j] * ndv + bias[off + j];
        if (RELU) o = fmaxf(o, 0.f);
        if (OUT_BF16) ((u16*)out_all)[(size_t)enc * NN * F + (size_t)node * F + off + j] = f2bf_u16(o);
        else ((float*)out_all)[(size_t)enc * NN * F + (size_t)node * F + off + j] = o;
    }
}

// ---------------- normalize + build R ----------------

__global__ __launch_bounds__(256)
void build_r_kernel(const float* __restrict__ H2a, const float* __restrict__ H2b,
                    const int* __restrict__ index, u16* __restrict__ R) {
    int lane = threadIdx.x & 63;
    int row = blockIdx.x * 4 + (threadIdx.x >> 6);
    int g = index[row];
    float2 a = *(const float2*)(H2a + (size_t)g * 128 + lane * 2);
    float2 b = *(const float2*)(H2b + (size_t)g * 128 + lane * 2);
    float sa = a.x * a.x + a.y * a.y;
    float sb = b.x * b.x + b.y * b.y;
    #pragma unroll
    for (int d = 1; d < 64; d <<= 1) {
        sa += __shfl_xor(sa, d, 64);
        sb += __shfl_xor(sb, d, 64);
    }
    float inva = 1.f / fmaxf(sqrtf(sa), 1e-12f);
    float invb = 1.f / fmaxf(sqrtf(sb), 1e-12f);
    float ax = a.x * inva, ay = a.y * inva;
    float bx = b.x * invb, by = b.y * invb;
    const float c2 = 0.5f, c3 = 0.28867513459481287f;  // 1/(2*sqrt(3))
    u16* Rp = R + (size_t)row * 256;
    Rp[lane * 2]           = f2bf_u16((ax + bx) * c2);
    Rp[lane * 2 + 1]       = f2bf_u16((ay + by) * c2);
    Rp[128 + lane * 2]     = f2bf_u16((ax - bx) * c3);
    Rp[128 + lane * 2 + 1] = f2bf_u16((ay - by) * c3);
}

// ---------------- launch ----------------

extern "C" void kernel_launch(void* const* d_in, const int* in_sizes, int n_in,
                              void* d_out, int out_size, void* d_ws, size_t ws_size,
                              hipStream_t stream) {
    (void)in_sizes; (void)n_in; (void)out_size; (void)ws_size;
    const float* raw0 = (const float*)d_in[0];
    const float* raw1 = (const float*)d_in[1];
    const int* src1 = (const int*)d_in[2], *dst1 = (const int*)d_in[3];
    const int* src2 = (const int*)d_in[4], *dst2 = (const int*)d_in[5];
    const int* index = (const int*)d_in[6];
    const float* W1a = (const float*)d_in[7];  const float* b1a = (const float*)d_in[8];
    const float* W2a = (const float*)d_in[9];  const float* b2a = (const float*)d_in[10];
    const float* W1b = (const float*)d_in[11]; const float* b1b = (const float*)d_in[12];
    const float* W2b = (const float*)d_in[13]; const float* b2b = (const float*)d_in[14];

    char* wp = (char*)d_ws;
    auto alloc = [&](size_t bytes) -> char* {
        char* r = wp;
        wp += (bytes + 255) & ~(size_t)255;
        return r;
    };
    float* norms   = (float*)alloc((size_t)4 * NN * 4);
    int*   deg2    = (int*)alloc((size_t)2 * NK * 4);
    int*   rp2     = (int*)alloc((size_t)2 * (NK + 1) * 4);
    int*   cur2    = (int*)alloc((size_t)2 * NK * 4);
    int*   tot     = (int*)alloc((size_t)2 * SAB * 4);
    int*   bcur    = (int*)alloc(32 * 4);
    u16*   csr_all = (u16*)alloc((size_t)2 * NE * 2);
    u16*   W1t     = (u16*)alloc((size_t)2 * 512 * 256 * 2);
    u16*   W2t     = (u16*)alloc((size_t)2 * 256 * 128 * 2);
    u16*   Y1      = (u16*)alloc((size_t)2 * NN * 256 * 2);
    u16*   H1      = (u16*)alloc((size_t)2 * NN * 256 * 2);
    u16*   Y2      = (u16*)alloc((size_t)2 * NN * 128 * 2);
    float* H2      = (float*)alloc((size_t)2 * NN * 128 * 4);
    u16*   R       = (u16*)alloc((size_t)NIDX * 256 * 2);
    // aliases (dead ranges at time of use):
    u32* partial2    = (u32*)Y1;
    u32* partial_out = (u32*)H1;
    u32* ebuf_d      = (u32*)Y2;
    u16* ebuf_s      = (u16*)H2;

    const int MT = (NN + 127) / 128;  // 391 row tiles

    hipMemsetAsync(bcur, 0, 32 * 4, stream);
    convw_kernel<<<dim3((512 * 256 + 255) / 256, 4), 256, 0, stream>>>(W1a, W1b, W2a, W2b, W1t, W2t);
    partition_kernel<<<dim3(PGX, 2), 256, 0, stream>>>(src1, dst1, src2, dst2, bcur, ebuf_d, ebuf_s);
    bhist_kernel<<<dim3(8 * HCH, 4), 256, 0, stream>>>(ebuf_d, ebuf_s, bcur, partial2, partial_out);
    reduce_hist_kernel<<<(2 * NN + 255) / 256, 256, 0, stream>>>(partial2, partial_out, deg2, norms);
    scanA_kernel<<<dim3(SAB, 2), 1024, 0, stream>>>(deg2, rp2, tot);
    scanC_kernel<<<dim3((NK / 4 + 255) / 256, 2), 256, 0, stream>>>(rp2, cur2, tot);
    scatter_kernel<<<dim3(8 * 64, 2), 256, 0, stream>>>(ebuf_d, bcur, cur2, csr_all);

    // Y1 = (raw @ W1) * ns[row]   (both encoders, row-major)
    gemm_kernel<true, true, false, true><<<dim3(MT, 2, 2), 256, 0, stream>>>(
        raw0, raw1, W1t, W1t + (size_t)512 * 256, Y1, Y1 + (size_t)NN * 256,
        norms, norms + (size_t)2 * NN, NN, 256, 512);
    // H1 = relu(nd * agg(Y1) + b1), both encs in one dispatch; z lower-tri filled alongside
    agg_kernel<256, true, true, true><<<dim3(ZHB + AGB, 2), 256, 0, stream>>>(
        Y1, rp2, csr_all, norms, b1a, b1b, H1, (float*)d_out);
    // Y2 = (H1 @ W2) * ns[row]
    gemm_kernel<false, true, false, true><<<dim3(MT, 1, 2), 256, 0, stream>>>(
        H1, H1 + (size_t)NN * 256, W2t, W2t + (size_t)256 * 128, Y2, Y2 + (size_t)NN * 128,
        norms, norms + (size_t)2 * NN, NN, 128, 256);
    // H2 = nd * agg(Y2) + b2, f32, both encs
    agg_kernel<128, false, false, false><<<dim3(AGB, 2), 256, 0, stream>>>(
        Y2, rp2, csr_all, norms, b2a, b2b, H2, nullptr);

    // R = [ (c1n+c2n)/2 , (c1n-c2n)/(2*sqrt(3)) ]  (8192 x 256, bf16)
    build_r_kernel<<<NIDX / 4, 256, 0, stream>>>(H2, H2 + (size_t)NN * 128, index, R);
    // z = triu(R @ R^T): upper-tri tiles only (lower filled during agg1)
    gemm_kernel<false, false, true, false><<<dim3(ZUB, 1, 1), 256, 0, stream>>>(
        R, R, R, R, (float*)d_out, (float*)d_out, nullptr, nullptr, NIDX, NIDX, 256);
}

// Round 16
// 624.019 us; speedup vs baseline: 1.4042x; 1.0559x over previous
//
#include <hip/hip_runtime.h>
#include <hip/hip_bf16.h>

using u16 = unsigned short;
using u32 = unsigned int;

typedef __attribute__((ext_vector_type(8))) short short8;
typedef __attribute__((ext_vector_type(4))) float f32x4;

__device__ __forceinline__ u16 f2bf_u16(float f) {
    __hip_bfloat16 h = __float2bfloat16(f);
    return __builtin_bit_cast(u16, h);
}
__device__ __forceinline__ float bfu(u32 u) { return __uint_as_float(u << 16); }

static constexpr int NN = 50000;
static constexpr int NE = 1600000;
static constexpr int NIDX = 8192;
static constexpr int NRANGE = 8;
static constexpr int RN = NN / NRANGE;
static constexpr int HCH = 16;
static constexpr int NK = NN * NRANGE;
static constexpr int SAB = (NK + 4095) / 4096;
static constexpr int CAPB = 262144;
static constexpr int PEB = 8192;
static constexpr int PGX = (NE + PEB - 1) / PEB;  // 196
static constexpr int CVB = 640;               // convw blocks per enc-slice (2*640*256 = 327680 elems)
static constexpr int PSTG = 1536;
static constexpr int ZLB = 64 * 63 / 2;       // 2016 lower-tri z tiles
static constexpr int ZHB = ZLB / 2;           // 1008 fill tiles per enc-row of agg1
static constexpr int ZUB = 64 * 65 / 2;       // 2080 upper-tri z tiles
static constexpr int AGB = NN / 4;            // 12500 node-groups per enc
static constexpr int MT = (NN + 127) / 128;   // 391 row tiles
static constexpr int SCX = 256;               // scatter x-extension of gemm1 grid (x4 slices = 1024)

// ---------------- partition (+ fused convw): one edge read -> per-range buckets ----------------

__global__ __launch_bounds__(256)
void partition_kernel(const int* __restrict__ s1, const int* __restrict__ d1,
                      const int* __restrict__ s2, const int* __restrict__ d2,
                      int* __restrict__ bcur, u32* __restrict__ ebuf_d, u16* __restrict__ ebuf_s,
                      const float* __restrict__ W1a, const float* __restrict__ W1b,
                      const float* __restrict__ W2a, const float* __restrict__ W2b,
                      u16* __restrict__ W1t, u16* __restrict__ W2t) {
    if (blockIdx.x >= PGX) {
        // fused convw: transpose+cast the four weight mats ([K][N] f32 -> [N][K] bf16)
        int o = (blockIdx.x - PGX) + CVB * blockIdx.y;
        int idx = o * 256 + threadIdx.x;
        if (idx < 131072) {
            int k = idx >> 8, n = idx & 255;
            W1t[(size_t)n * 512 + k] = f2bf_u16(W1a[idx]);
        } else if (idx < 262144) {
            int j = idx - 131072;
            int k = j >> 8, n = j & 255;
            W1t[(size_t)131072 + (size_t)n * 512 + k] = f2bf_u16(W1b[j]);
        } else if (idx < 294912) {
            int j = idx - 262144;
            int k = j >> 7, n = j & 127;
            W2t[(size_t)n * 256 + k] = f2bf_u16(W2a[j]);
        } else if (idx < 327680) {
            int j = idx - 294912;
            int k = j >> 7, n = j & 127;
            W2t[(size_t)32768 + (size_t)n * 256 + k] = f2bf_u16(W2b[j]);
        }
        return;
    }
    __shared__ u32 stage_d[8][PSTG];
    __shared__ u16 stage_s[8][PSTG];
    __shared__ int cnt_d[8], cnt_s[8], base_d[8], base_s[8];
    int enc = blockIdx.y;
    const int* s = enc ? s2 : s1;
    const int* d = enc ? d2 : d1;
    if (threadIdx.x < 8) { cnt_d[threadIdx.x] = 0; cnt_s[threadIdx.x] = 0; }
    __syncthreads();
    int* bc_d = bcur + enc * 16;
    int* bc_s = bcur + enc * 16 + 8;
    u32* bd = ebuf_d + (size_t)enc * 8 * CAPB;
    u16* bs = ebuf_s + (size_t)enc * 8 * CAPB;
    int e0 = blockIdx.x * PEB;
    int e1 = min(e0 + PEB, NE);
    for (int e = e0 + threadIdx.x * 4; e < e1; e += 1024) {
        int4 sv = *(const int4*)(s + e);
        int4 dv = *(const int4*)(d + e);
        #pragma unroll
        for (int j = 0; j < 4; ++j) {
            int src = j == 0 ? sv.x : j == 1 ? sv.y : j == 2 ? sv.z : sv.w;
            int dst = j == 0 ? dv.x : j == 1 ? dv.y : j == 2 ? dv.z : dv.w;
            int rd = dst / RN;
            u32 entry = (u32)src | ((u32)(dst - rd * RN) << 16);
            int slot = atomicAdd(&cnt_d[rd], 1);
            if (slot < PSTG) stage_d[rd][slot] = entry;
            else { int gp = atomicAdd(&bc_d[rd], 1); bd[(size_t)rd * CAPB + gp] = entry; }
            int rs = src / RN;
            int slot2 = atomicAdd(&cnt_s[rs], 1);
            if (slot2 < PSTG) stage_s[rs][slot2] = (u16)(src - rs * RN);
            else { int gp = atomicAdd(&bc_s[rs], 1); bs[(size_t)rs * CAPB + gp] = (u16)(src - rs * RN); }
        }
    }
    __syncthreads();
    if (threadIdx.x < 8) {
        int b = threadIdx.x;
        base_d[b] = atomicAdd(&bc_d[b], min(cnt_d[b], PSTG));
        base_s[b] = atomicAdd(&bc_s[b], min(cnt_s[b], PSTG));
    }
    __syncthreads();
    #pragma unroll
    for (int b = 0; b < 8; ++b) {
        int nb = min(cnt_d[b], PSTG);
        for (int i = threadIdx.x; i < nb; i += 256)
            bd[(size_t)b * CAPB + base_d[b] + i] = stage_d[b][i];
        int ns = min(cnt_s[b], PSTG);
        for (int i = threadIdx.x; i < ns; i += 256)
            bs[(size_t)b * CAPB + base_s[b] + i] = stage_s[b][i];
    }
}

// ---------------- bucket hist ----------------

__global__ __launch_bounds__(256)
void bhist_kernel(const u32* __restrict__ ebuf_d, const u16* __restrict__ ebuf_s,
                  const int* __restrict__ bcur,
                  u32* __restrict__ partial2, u32* __restrict__ partial_out) {
    __shared__ u32 sh[RN * 2];
    int stripe = blockIdx.x & 7, chunk = blockIdx.x >> 3;
    int enc = blockIdx.y & 1, type = blockIdx.y >> 1;
    if (type == 0) {
        for (int i = threadIdx.x; i < RN * 2; i += 256) sh[i] = 0;
        __syncthreads();
        int size = bcur[enc * 16 + stripe];
        int cs = (size + HCH - 1) / HCH;
        int lo = chunk * cs, hi = min(lo + cs, size);
        const u32* b = ebuf_d + ((size_t)enc * 8 + stripe) * CAPB;
        for (int i = lo + threadIdx.x; i < hi; i += 256) {
            u32 e = b[i];
            u32 idx = (e >> 16) * 8 + (e & 0xffffu) / RN;
            atomicAdd(&sh[idx >> 2], 1u << ((idx & 3) * 8));
        }
        __syncthreads();
        u32* p2 = partial2 + ((size_t)enc * HCH + chunk) * (NN * 2) + stripe * (RN * 2);
        for (int i = threadIdx.x; i < RN * 2; i += 256) p2[i] = sh[i];
    } else {
        for (int i = threadIdx.x; i < RN / 2; i += 256) sh[i] = 0;
        __syncthreads();
        int size = bcur[enc * 16 + 8 + stripe];
        int cs = (size + HCH - 1) / HCH;
        int lo = chunk * cs, hi = min(lo + cs, size);
        const u16* b = ebuf_s + ((size_t)enc * 8 + stripe) * CAPB;
        for (int i = lo + threadIdx.x; i < hi; i += 256) {
            u32 sl = b[i];
            atomicAdd(&sh[sl >> 1], 1u << ((sl & 1) * 16));
        }
        __syncthreads();
        u32* po = partial_out + ((size_t)enc * HCH + chunk) * (NN / 2) + stripe * (RN / 2);
        for (int i = threadIdx.x; i < RN / 2; i += 256) po[i] = sh[i];
    }
}

__global__ void reduce_hist_kernel(const u32* __restrict__ partial2,
                                   const u32* __restrict__ partial_out,
                                   int* __restrict__ deg2, float* __restrict__ norms) {
    int i = blockIdx.x * blockDim.x + threadIdx.x;
    if (i >= 2 * NN) return;
    int enc = i / NN;
    int dst = i - enc * NN;
    int cnt[8];
    #pragma unroll
    for (int r = 0; r < 8; ++r) cnt[r] = 0;
    for (int c = 0; c < HCH; ++c) {
        const u32* p = partial2 + ((size_t)enc * HCH + c) * (NN * 2) + dst * 2;
        u32 w0 = p[0], w1 = p[1];
        cnt[0] += w0 & 0xff; cnt[1] += (w0 >> 8) & 0xff; cnt[2] += (w0 >> 16) & 0xff; cnt[3] += w0 >> 24;
        cnt[4] += w1 & 0xff; cnt[5] += (w1 >> 8) & 0xff; cnt[6] += (w1 >> 16) & 0xff; cnt[7] += w1 >> 24;
    }
    int* dp = deg2 + (size_t)enc * NK + dst * 8;
    int din = 0;
    #pragma unroll
    for (int r = 0; r < 8; ++r) { dp[r] = cnt[r]; din += cnt[r]; }
    norms[(enc * 2 + 1) * NN + dst] = rsqrtf(fmaxf((float)din, 1.f));
    int dout = 0;
    for (int c = 0; c < HCH; ++c) {
        u32 w = partial_out[((size_t)enc * HCH + c) * (NN / 2) + (dst >> 1)];
        dout += (w >> ((dst & 1) * 16)) & 0xffff;
    }
    norms[(enc * 2 + 0) * NN + dst] = rsqrtf(fmaxf((float)dout, 1.f));
}

// ---------------- 2-phase scan ----------------

__global__ __launch_bounds__(1024)
void scanA_kernel(const int* __restrict__ deg2, int* __restrict__ rp2_all, int* __restrict__ tot) {
    int enc = blockIdx.y;
    const int* deg = deg2 + (size_t)enc * NK;
    int* rp = rp2_all + (size_t)enc * (NK + 1);
    __shared__ int wsum[16];
    int t = threadIdx.x, lane = t & 63, wid = t >> 6;
    int i0 = blockIdx.x * 4096 + t * 4;
    int4 v = make_int4(0, 0, 0, 0);
    bool in = (i0 + 3 < NK);
    if (in) v = *(const int4*)(deg + i0);
    int s = v.x + v.y + v.z + v.w;
    int x = s;
    #pragma unroll
    for (int d = 1; d < 64; d <<= 1) {
        int y = __shfl_up(x, d, 64);
        if (lane >= d) x += y;
    }
    if (lane == 63) wsum[wid] = x;
    __syncthreads();
    if (t == 0) {
        int run = 0;
        #pragma unroll
        for (int w = 0; w < 16; ++w) { int q = wsum[w]; wsum[w] = run; run += q; }
        tot[enc * SAB + blockIdx.x] = run;
    }
    __syncthreads();
    if (in) {
        int excl = wsum[wid] + x - s;
        rp[i0] = excl;
        rp[i0 + 1] = excl + v.x;
        rp[i0 + 2] = excl + v.x + v.y;
        rp[i0 + 3] = excl + v.x + v.y + v.z;
    }
}

__global__ __launch_bounds__(256)
void scanC_kernel(int* __restrict__ rp2_all, int* __restrict__ cur2_all, const int* __restrict__ tot) {
    int enc = blockIdx.y;
    int* rp = rp2_all + (size_t)enc * (NK + 1);
    int* cur = cur2_all + (size_t)enc * NK;
    int nA = blockIdx.x >> 2;
    int part = 0;
    for (int i = threadIdx.x; i < nA; i += 256) part += tot[enc * SAB + i];
    #pragma unroll
    for (int d = 1; d < 64; d <<= 1) part += __shfl_xor(part, d, 64);
    __shared__ int red[4];
    __shared__ int soff;
    int lane = threadIdx.x & 63, wv = threadIdx.x >> 6;
    if (lane == 0) red[wv] = part;
    __syncthreads();
    if (threadIdx.x == 0) soff = red[0] + red[1] + red[2] + red[3];
    __syncthreads();
    int off = soff;
    int idx = (blockIdx.x * 256 + threadIdx.x) * 4;
    if (idx < NK) {
        int4 v = *(const int4*)(rp + idx);
        v.x += off; v.y += off; v.z += off; v.w += off;
        *(int4*)(rp + idx) = v;
        *(int4*)(cur + idx) = v;
    }
    if (blockIdx.x == 0 && threadIdx.x == 0) rp[NK] = NE;
}

// ---------------- scatter body (XCD-pinned via caller-provided stripe) ----------------

__device__ __forceinline__ void scatter_body(const u32* __restrict__ ebuf_d,
                                             const int* __restrict__ bcur,
                                             int* __restrict__ cur2_all, u16* __restrict__ csr_all,
                                             int stripe, int chunk, int enc) {
    int size = bcur[enc * 16 + stripe];
    int cs = (size + 63) / 64;
    int lo = chunk * cs, hi = min(lo + cs, size);
    const u32* b = ebuf_d + ((size_t)enc * 8 + stripe) * CAPB;
    int* cursor = cur2_all + (size_t)enc * NK;
    u16* csr = csr_all + (size_t)enc * NE;
    int base = stripe * RN;
    for (int i = lo + threadIdx.x; i < hi; i += 256) {
        u32 e = b[i];
        int src = e & 0xffff;
        int dst = base + (int)(e >> 16);
        int key = dst * 8 + src / RN;
        int pos = atomicAdd(&cursor[key], 1);
        csr[pos] = (u16)src;
    }
}

// ---------------- MFMA GEMM device body: 2-deep pipeline, LDS-repacked epilogue ----------------

template<bool A_F32, bool OUT_BF16, bool TRIANG, bool SCALE>
__device__ __forceinline__ void gemm_device(const void* __restrict__ A_, const u16* __restrict__ Bt,
                                            void* __restrict__ C_, const float* __restrict__ rowscale,
                                            int M, int N, int K, int it, int jt, u16* smem) {
    int t = threadIdx.x;
    int brow = it * 128, bcol = jt * 128;
    float* Cf = (float*)C_;
    u16* As = smem;
    u16* Bs = smem + 128 * 40;
    int lane = t & 63, wv = t >> 6;
    int wr = wv >> 1, wc = wv & 1;
    f32x4 acc[4][4];
    #pragma unroll
    for (int m = 0; m < 4; ++m)
        #pragma unroll
        for (int n = 0; n < 4; ++n) acc[m][n] = f32x4{0.f, 0.f, 0.f, 0.f};

    float4 a_f0[4], a_f1[4];
    uint4  a_h0[2], a_h1[2];
    uint4  b_h0[2], b_h1[2];

#define LOADT(S, kk) do {                                                          \
    if constexpr (A_F32) {                                                         \
        const float* A = (const float*)A_;                                         \
        _Pragma("unroll")                                                          \
        for (int p = 0; p < 4; ++p) {                                              \
            int r = p * 32 + (t >> 3), c = (t & 7) * 4;                            \
            int gr = brow + r;                                                     \
            a_f##S[p] = make_float4(0.f, 0.f, 0.f, 0.f);                           \
            if (gr < M) a_f##S[p] = *(const float4*)(A + (size_t)gr * K + (kk) + c); \
        }                                                                          \
    } else {                                                                       \
        const u16* A = (const u16*)A_;                                             \
        _Pragma("unroll")                                                          \
        for (int p = 0; p < 2; ++p) {                                              \
            int r = p * 64 + (t >> 2), c = (t & 3) * 8;                            \
            int gr = brow + r;                                                     \
            a_h##S[p] = make_uint4(0u, 0u, 0u, 0u);                                \
            if (gr < M) a_h##S[p] = *(const uint4*)(A + (size_t)gr * K + (kk) + c); \
        }                                                                          \
    }                                                                              \
    _Pragma("unroll")                                                              \
    for (int p = 0; p < 2; ++p) {                                                  \
        int r = p * 64 + (t >> 2), c = (t & 3) * 8;                                \
        int gn = bcol + r;                                                         \
        b_h##S[p] = make_uint4(0u, 0u, 0u, 0u);                                    \
        if (gn < N) b_h##S[p] = *(const uint4*)(Bt + (size_t)gn * K + (kk) + c);   \
    }                                                                              \
} while (0)

#define STORET(S) do {                                                             \
    if constexpr (A_F32) {                                                         \
        _Pragma("unroll")                                                          \
        for (int p = 0; p < 4; ++p) {                                              \
            int r = p * 32 + (t >> 3), c = (t & 7) * 4;                            \
            u32 lo = (u32)f2bf_u16(a_f##S[p].x) | ((u32)f2bf_u16(a_f##S[p].y) << 16); \
            u32 hi = (u32)f2bf_u16(a_f##S[p].z) | ((u32)f2bf_u16(a_f##S[p].w) << 16); \
            *(uint2*)&As[r * 40 + c] = make_uint2(lo, hi);                         \
        }                                                                          \
    } else {                                                                       \
        _Pragma("unroll")                                                          \
        for (int p = 0; p < 2; ++p) {                                              \
            int r = p * 64 + (t >> 2), c = (t & 3) * 8;                            \
            *(uint4*)&As[r * 40 + c] = a_h##S[p];                                  \
        }                                                                          \
    }                                                                              \
    _Pragma("unroll")                                                              \
    for (int p = 0; p < 2; ++p) {                                                  \
        int r = p * 64 + (t >> 2), c = (t & 3) * 8;                                \
        *(uint4*)&Bs[r * 40 + c] = b_h##S[p];                                      \
    }                                                                              \
} while (0)

    auto compute = [&]() {
        int kg = (lane >> 4) * 8;
        short8 av[4], bv[4];
        #pragma unroll
        for (int m = 0; m < 4; ++m)
            av[m] = *(const short8*)&As[(wr * 64 + m * 16 + (lane & 15)) * 40 + kg];
        #pragma unroll
        for (int n = 0; n < 4; ++n)
            bv[n] = *(const short8*)&Bs[(wc * 64 + n * 16 + (lane & 15)) * 40 + kg];
        #pragma unroll
        for (int m = 0; m < 4; ++m)
            #pragma unroll
            for (int n = 0; n < 4; ++n)
                acc[m][n] = __builtin_amdgcn_mfma_f32_16x16x32_bf16(av[m], bv[n], acc[m][n], 0, 0, 0);
    };

    LOADT(0, 0);
    LOADT(1, 32);
    for (int k0 = 0; k0 < K; k0 += 64) {
        STORET(0);
        __syncthreads();
        if (k0 + 64 < K) LOADT(0, k0 + 64);
        compute();
        __syncthreads();
        STORET(1);
        __syncthreads();
        if (k0 + 96 < K) LOADT(1, k0 + 96);
        compute();
        __syncthreads();
    }
#undef LOADT
#undef STORET

    const int lane15 = lane & 15, lanehi = lane >> 4;
    if (OUT_BF16) {
        u16* stg = smem + wv * 1024;
        #pragma unroll
        for (int m = 0; m < 4; ++m) {
            #pragma unroll
            for (int n = 0; n < 4; ++n)
                #pragma unroll
                for (int r = 0; r < 4; ++r) {
                    float v = acc[m][n][r];
                    if (SCALE) v *= rowscale[brow + wr * 64 + m * 16 + lanehi * 4 + r];
                    stg[(lanehi * 4 + r) * 64 + n * 16 + lane15] = f2bf_u16(v);
                }
            #pragma unroll
            for (int pass = 0; pass < 2; ++pass) {
                int lr = pass * 8 + (lane >> 3);
                int grow = brow + wr * 64 + m * 16 + lr;
                uint4 w = *(uint4*)&stg[lr * 64 + (lane & 7) * 8];
                if (grow < M)
                    *(uint4*)((u16*)C_ + (size_t)grow * N + bcol + wc * 64 + (lane & 7) * 8) = w;
            }
        }
    } else {
        float* stg = (float*)smem + wv * 1024;
        #pragma unroll
        for (int m = 0; m < 4; ++m) {
            #pragma unroll
            for (int n = 0; n < 4; ++n)
                #pragma unroll
                for (int r = 0; r < 4; ++r) {
                    int row = brow + wr * 64 + m * 16 + lanehi * 4 + r;
                    int col = bcol + wc * 64 + n * 16 + lane15;
                    float v = acc[m][n][r];
                    if (SCALE) v *= rowscale[row];
                    if (TRIANG && col < row) v = 0.f;
                    stg[(lanehi * 4 + r) * 64 + n * 16 + lane15] = v;
                }
            #pragma unroll
            for (int pass = 0; pass < 4; ++pass) {
                int lr = pass * 4 + lanehi;
                int grow = brow + wr * 64 + m * 16 + lr;
                f32x4 w = *(f32x4*)&stg[lr * 64 + lane15 * 4];
                if (grow < M) {
                    float* dp = Cf + (size_t)grow * N + bcol + wc * 64 + lane15 * 4;
                    if (TRIANG) __builtin_nontemporal_store(w, (f32x4*)dp);
                    else *(f32x4*)dp = w;
                }
            }
        }
    }
}

// gemm1 fused with scatter: grid (MT + SCX, 2, 2); x >= MT blocks do XCD-pinned scatter.
__global__ __launch_bounds__(256)
void gemm1scat_kernel(const float* __restrict__ raw0, const float* __restrict__ raw1,
                      const u16* __restrict__ W1t, u16* __restrict__ Y1,
                      const float* __restrict__ norms,
                      const u32* __restrict__ ebuf_d, const int* __restrict__ bcur,
                      int* __restrict__ tick, int* __restrict__ cur2, u16* __restrict__ csr_all) {
    if (blockIdx.x >= MT) {
        // stripe fixed by hardware block linearization -> XCD pinning; ticket picks (enc, chunk)
        u32 lin = blockIdx.x + gridDim.x * (blockIdx.y + gridDim.y * blockIdx.z);
        int stripe = lin & 7;
        __shared__ int tsh;
        if (threadIdx.x == 0) tsh = atomicAdd(&tick[stripe], 1);
        __syncthreads();
        int tkt = tsh;               // 0..127 per stripe: enc = tkt>>6, chunk = tkt&63
        scatter_body(ebuf_d, bcur, cur2, csr_all, stripe, tkt & 63, tkt >> 6);
        return;
    }
    __shared__ alignas(16) u16 smem[128 * 40 * 2];
    int enc = blockIdx.z;
    gemm_device<true, true, false, true>(
        enc ? raw1 : raw0, W1t + (size_t)enc * 512 * 256,
        Y1 + (size_t)enc * NN * 256, norms + (size_t)2 * enc * NN,
        NN, 256, 512, blockIdx.x, blockIdx.y, smem);
}

// gemm2 (dual-enc)
__global__ __launch_bounds__(256)
void gemm2_kernel(const u16* __restrict__ H1, const u16* __restrict__ W2t,
                  u16* __restrict__ Y2, const float* __restrict__ norms) {
    __shared__ alignas(16) u16 smem[128 * 40 * 2];
    int enc = blockIdx.z;
    gemm_device<false, true, false, true>(
        H1 + (size_t)enc * NN * 256, W2t + (size_t)enc * 256 * 128,
        Y2 + (size_t)enc * NN * 128, norms + (size_t)2 * enc * NN,
        NN, 128, 256, blockIdx.x, 0, smem);
}

// z = triu(R @ R^T): 1D upper-tri grid
__global__ __launch_bounds__(256)
void zgemm_kernel(const u16* __restrict__ R, float* __restrict__ out) {
    int b = blockIdx.x;
    int i = (int)((129.0f - sqrtf(129.f * 129.f - 8.f * b)) * 0.5f);
    while ((i + 1) * (129 - (i + 1)) / 2 <= b) ++i;
    while (i * (129 - i) / 2 > b) --i;
    int it = i;
    int jt = i + (b - i * (129 - i) / 2);
    __shared__ alignas(16) u16 smem[128 * 40 * 2];
    gemm_device<false, false, true, false>(R, R, out, nullptr, NIDX, NIDX, 256, it, jt, smem);
}

// ---------------- row-major aggregation, dual-enc (grid.y = enc) ----------------

template<int F, bool RELU, bool OUT_BF16, bool ZFILL>
__global__ __launch_bounds__(256)
void agg_kernel(const u16* __restrict__ Yall, const int* __restrict__ rp2_all,
                const u16* __restrict__ csr_all, const float* __restrict__ norms,
                const float* __restrict__ bias0, const float* __restrict__ bias1,
                void* __restrict__ out_all, float* __restrict__ zout) {
    constexpr int VPL = F / 64;
    int enc = blockIdx.y;
    int bid = blockIdx.x;
    if (ZFILL) {
        if (bid < ZHB) {
            int b = enc * ZHB + bid;
            float fit = (sqrtf(8.f * b + 1.f) + 1.f) * 0.5f;
            int it = (int)fit;
            if (it * (it - 1) / 2 > b) --it;
            else if ((it + 1) * it / 2 <= b) ++it;
            int jt = b - it * (it - 1) / 2;
            int brow = it * 128, bcol = jt * 128;
            f32x4 z = {0.f, 0.f, 0.f, 0.f};
            #pragma unroll
            for (int pq = 0; pq < 16; ++pq) {
                int idx = pq * 256 + threadIdx.x;
                int r = idx >> 5, c4 = idx & 31;
                __builtin_nontemporal_store(z, (f32x4*)(zout + (size_t)(brow + r) * NIDX + bcol + c4 * 4));
            }
            return;
        }
        bid -= ZHB;
    }
    const u16* Y = Yall + (size_t)enc * NN * F;
    const int* rp2 = rp2_all + (size_t)enc * (NK + 1);
    const u16* csr = csr_all + (size_t)enc * NE;
    const float* nd = norms + (size_t)(2 * enc + 1) * NN;
    const float* bias = enc ? bias1 : bias0;
    int lane = threadIdx.x & 63;
    int node = bid * 4 + (threadIdx.x >> 6);
    int e0 = rp2[node * 8], e1 = rp2[node * 8 + 8];
    float acc[VPL];
    #pragma unroll
    for (int j = 0; j < VPL; ++j) acc[j] = 0.f;
    const int off = lane * VPL;

    int e = e0;
    for (; e < e1 && (e & 7) != 0; ++e) {
        int s = csr[e];
        if (VPL == 4) {
            uint2 d = *(const uint2*)(Y + (size_t)s * F + off);
            acc[0] += bfu(d.x & 0xffffu); acc[1] += bfu(d.x >> 16);
            acc[2] += bfu(d.y & 0xffffu); acc[3] += bfu(d.y >> 16);
        } else {
            u32 d = *(const u32*)(Y + (size_t)s * F + off);
            acc[0] += bfu(d & 0xffffu); acc[1] += bfu(d >> 16);
        }
    }
    if (VPL == 4) {
        for (; e + 16 <= e1; e += 16) {
            uint4 ia = *(const uint4*)(csr + e);
            uint4 ib = *(const uint4*)(csr + e + 8);
            int s0 = ia.x & 0xffff, s1 = ia.x >> 16, s2 = ia.y & 0xffff, s3 = ia.y >> 16;
            int s4 = ia.z & 0xffff, s5 = ia.z >> 16, s6 = ia.w & 0xffff, s7 = ia.w >> 16;
            int s8 = ib.x & 0xffff, s9 = ib.x >> 16, sa = ib.y & 0xffff, sb = ib.y >> 16;
            int sc = ib.z & 0xffff, sd = ib.z >> 16, se = ib.w & 0xffff, sf = ib.w >> 16;
            uint2 d0 = *(const uint2*)(Y + (size_t)s0 * F + off);
            uint2 d1 = *(const uint2*)(Y + (size_t)s1 * F + off);
            uint2 d2 = *(const uint2*)(Y + (size_t)s2 * F + off);
            uint2 d3 = *(const uint2*)(Y + (size_t)s3 * F + off);
            uint2 d4 = *(const uint2*)(Y + (size_t)s4 * F + off);
            uint2 d5 = *(const uint2*)(Y + (size_t)s5 * F + off);
            uint2 d6 = *(const uint2*)(Y + (size_t)s6 * F + off);
            uint2 d7 = *(const uint2*)(Y + (size_t)s7 * F + off);
            uint2 d8 = *(const uint2*)(Y + (size_t)s8 * F + off);
            uint2 d9 = *(const uint2*)(Y + (size_t)s9 * F + off);
            uint2 da = *(const uint2*)(Y + (size_t)sa * F + off);
            uint2 db = *(const uint2*)(Y + (size_t)sb * F + off);
            uint2 dc = *(const uint2*)(Y + (size_t)sc * F + off);
            uint2 dd = *(const uint2*)(Y + (size_t)sd * F + off);
            uint2 de = *(const uint2*)(Y + (size_t)se * F + off);
            uint2 df = *(const uint2*)(Y + (size_t)sf * F + off);
            acc[0] += bfu(d0.x & 0xffffu); acc[1] += bfu(d0.x >> 16); acc[2] += bfu(d0.y & 0xffffu); acc[3] += bfu(d0.y >> 16);
            acc[0] += bfu(d1.x & 0xffffu); acc[1] += bfu(d1.x >> 16); acc[2] += bfu(d1.y & 0xffffu); acc[3] += bfu(d1.y >> 16);
            acc[0] += bfu(d2.x & 0xffffu); acc[1] += bfu(d2.x >> 16); acc[2] += bfu(d2.y & 0xffffu); acc[3] += bfu(d2.y >> 16);
            acc[0] += bfu(d3.x & 0xffffu); acc[1] += bfu(d3.x >> 16); acc[2] += bfu(d3.y & 0xffffu); acc[3] += bfu(d3.y >> 16);
            acc[0] += bfu(d4.x & 0xffffu); acc[1] += bfu(d4.x >> 16); acc[2] += bfu(d4.y & 0xffffu); acc[3] += bfu(d4.y >> 16);
            acc[0] += bfu(d5.x & 0xffffu); acc[1] += bfu(d5.x >> 16); acc[2] += bfu(d5.y & 0xffffu); acc[3] += bfu(d5.y >> 16);
            acc[0] += bfu(d6.x & 0xffffu); acc[1] += bfu(d6.x >> 16); acc[2] += bfu(d6.y & 0xffffu); acc[3] += bfu(d6.y >> 16);
            acc[0] += bfu(d7.x & 0xffffu); acc[1] += bfu(d7.x >> 16); acc[2] += bfu(d7.y & 0xffffu); acc[3] += bfu(d7.y >> 16);
            acc[0] += bfu(d8.x & 0xffffu); acc[1] += bfu(d8.x >> 16); acc[2] += bfu(d8.y & 0xffffu); acc[3] += bfu(d8.y >> 16);
            acc[0] += bfu(d9.x & 0xffffu); acc[1] += bfu(d9.x >> 16); acc[2] += bfu(d9.y & 0xffffu); acc[3] += bfu(d9.y >> 16);
            acc[0] += bfu(da.x & 0xffffu); acc[1] += bfu(da.x >> 16); acc[2] += bfu(da.y & 0xffffu); acc[3] += bfu(da.y >> 16);
            acc[0] += bfu(db.x & 0xffffu); acc[1] += bfu(db.x >> 16); acc[2] += bfu(db.y & 0xffffu); acc[3] += bfu(db.y >> 16);
            acc[0] += bfu(dc.x & 0xffffu); acc[1] += bfu(dc.x >> 16); acc[2] += bfu(dc.y & 0xffffu); acc[3] += bfu(dc.y >> 16);
            acc[0] += bfu(dd.x & 0xffffu); acc[1] += bfu(dd.x >> 16); acc[2] += bfu(dd.y & 0xffffu); acc[3] += bfu(dd.y >> 16);
            acc[0] += bfu(de.x & 0xffffu); acc[1] += bfu(de.x >> 16); acc[2] += bfu(de.y & 0xffffu); acc[3] += bfu(de.y >> 16);
            acc[0] += bfu(df.x & 0xffffu); acc[1] += bfu(df.x >> 16); acc[2] += bfu(df.y & 0xffffu); acc[3] += bfu(df.y >> 16);
        }
    }
    for (; e + 8 <= e1; e += 8) {
        uint4 iv = *(const uint4*)(csr + e);
        int s0 = iv.x & 0xffff, s1 = iv.x >> 16;
        int s2 = iv.y & 0xffff, s3 = iv.y >> 16;
        int s4 = iv.z & 0xffff, s5 = iv.z >> 16;
        int s6 = iv.w & 0xffff, s7 = iv.w >> 16;
        if (VPL == 4) {
            uint2 d0 = *(const uint2*)(Y + (size_t)s0 * F + off);
            uint2 d1 = *(const uint2*)(Y + (size_t)s1 * F + off);
            uint2 d2 = *(const uint2*)(Y + (size_t)s2 * F + off);
            uint2 d3 = *(const uint2*)(Y + (size_t)s3 * F + off);
            uint2 d4 = *(const uint2*)(Y + (size_t)s4 * F + off);
            uint2 d5 = *(const uint2*)(Y + (size_t)s5 * F + off);
            uint2 d6 = *(const uint2*)(Y + (size_t)s6 * F + off);
            uint2 d7 = *(const uint2*)(Y + (size_t)s7 * F + off);
            acc[0] += bfu(d0.x & 0xffffu); acc[1] += bfu(d0.x >> 16); acc[2] += bfu(d0.y & 0xffffu); acc[3] += bfu(d0.y >> 16);
            acc[0] += bfu(d1.x & 0xffffu); acc[1] += bfu(d1.x >> 16); acc[2] += bfu(d1.y & 0xffffu); acc[3] += bfu(d1.y >> 16);
            acc[0] += bfu(d2.x & 0xffffu); acc[1] += bfu(d2.x >> 16); acc[2] += bfu(d2.y & 0xffffu); acc[3] += bfu(d2.y >> 16);
            acc[0] += bfu(d3.x & 0xffffu); acc[1] += bfu(d3.x >> 16); acc[2] += bfu(d3.y & 0xffffu); acc[3] += bfu(d3.y >> 16);
            acc[0] += bfu(d4.x & 0xffffu); acc[1] += bfu(d4.x >> 16); acc[2] += bfu(d4.y & 0xffffu); acc[3] += bfu(d4.y >> 16);
            acc[0] += bfu(d5.x & 0xffffu); acc[1] += bfu(d5.x >> 16); acc[2] += bfu(d5.y & 0xffffu); acc[3] += bfu(d5.y >> 16);
            acc[0] += bfu(d6.x & 0xffffu); acc[1] += bfu(d6.x >> 16); acc[2] += bfu(d6.y & 0xffffu); acc[3] += bfu(d6.y >> 16);
            acc[0] += bfu(d7.x & 0xffffu); acc[1] += bfu(d7.x >> 16); acc[2] += bfu(d7.y & 0xffffu); acc[3] += bfu(d7.y >> 16);
        } else {
            u32 d0 = *(const u32*)(Y + (size_t)s0 * F + off);
            u32 d1 = *(const u32*)(Y + (size_t)s1 * F + off);
            u32 d2 = *(const u32*)(Y + (size_t)s2 * F + off);
            u32 d3 = *(const u32*)(Y + (size_t)s3 * F + off);
            u32 d4 = *(const u32*)(Y + (size_t)s4 * F + off);
            u32 d5 = *(const u32*)(Y + (size_t)s5 * F + off);
            u32 d6 = *(const u32*)(Y + (size_t)s6 * F + off);
            u32 d7 = *(const u32*)(Y + (size_t)s7 * F + off);
            acc[0] += bfu(d0 & 0xffffu); acc[1] += bfu(d0 >> 16);
            acc[0] += bfu(d1 & 0xffffu); acc[1] += bfu(d1 >> 16);
            acc[0] += bfu(d2 & 0xffffu); acc[1] += bfu(d2 >> 16);
            acc[0] += bfu(d3 & 0xffffu); acc[1] += bfu(d3 >> 16);
            acc[0] += bfu(d4 & 0xffffu); acc[1] += bfu(d4 >> 16);
            acc[0] += bfu(d5 & 0xffffu); acc[1] += bfu(d5 >> 16);
            acc[0] += bfu(d6 & 0xffffu); acc[1] += bfu(d6 >> 16);
            acc[0] += bfu(d7 & 0xffffu); acc[1] += bfu(d7 >> 16);
        }
    }
    for (; e < e1; ++e) {
        int s = csr[e];
        if (VPL == 4) {
            uint2 d = *(const uint2*)(Y + (size_t)s * F + off);
            acc[0] += bfu(d.x & 0xffffu); acc[1] += bfu(d.x >> 16);
            acc[2] += bfu(d.y & 0xffffu); acc[3] += bfu(d.y >> 16);
        } else {
            u32 d = *(const u32*)(Y + (size_t)s * F + off);
            acc[0] += bfu(d & 0xffffu); acc[1] += bfu(d >> 16);
        }
    }

    float ndv = nd[node];
    #pragma unroll
    for (int j = 0; j < VPL; ++j) {
        float o = acc[j] * ndv + bias[off + j];
        if (RELU) o = fmaxf(o, 0.f);
        if (OUT_BF16) ((u16*)out_all)[(size_t)enc * NN * F + (size_t)node * F + off + j] = f2bf_u16(o);
        else ((float*)out_all)[(size_t)enc * NN * F + (size_t)node * F + off + j] = o;
    }
}

// ---------------- normalize + build R ----------------

__global__ __launch_bounds__(256)
void build_r_kernel(const float* __restrict__ H2a, const float* __restrict__ H2b,
                    const int* __restrict__ index, u16* __restrict__ R) {
    int lane = threadIdx.x & 63;
    int row = blockIdx.x * 4 + (threadIdx.x >> 6);
    int g = index[row];
    float2 a = *(const float2*)(H2a + (size_t)g * 128 + lane * 2);
    float2 b = *(const float2*)(H2b + (size_t)g * 128 + lane * 2);
    float sa = a.x * a.x + a.y * a.y;
    float sb = b.x * b.x + b.y * b.y;
    #pragma unroll
    for (int d = 1; d < 64; d <<= 1) {
        sa += __shfl_xor(sa, d, 64);
        sb += __shfl_xor(sb, d, 64);
    }
    float inva = 1.f / fmaxf(sqrtf(sa), 1e-12f);
    float invb = 1.f / fmaxf(sqrtf(sb), 1e-12f);
    float ax = a.x * inva, ay = a.y * inva;
    float bx = b.x * invb, by = b.y * invb;
    const float c2 = 0.5f, c3 = 0.28867513459481287f;  // 1/(2*sqrt(3))
    u16* Rp = R + (size_t)row * 256;
    Rp[lane * 2]           = f2bf_u16((ax + bx) * c2);
    Rp[lane * 2 + 1]       = f2bf_u16((ay + by) * c2);
    Rp[128 + lane * 2]     = f2bf_u16((ax - bx) * c3);
    Rp[128 + lane * 2 + 1] = f2bf_u16((ay - by) * c3);
}

// ---------------- launch ----------------

extern "C" void kernel_launch(void* const* d_in, const int* in_sizes, int n_in,
                              void* d_out, int out_size, void* d_ws, size_t ws_size,
                              hipStream_t stream) {
    (void)in_sizes; (void)n_in; (void)out_size; (void)ws_size;
    const float* raw0 = (const float*)d_in[0];
    const float* raw1 = (const float*)d_in[1];
    const int* src1 = (const int*)d_in[2], *dst1 = (const int*)d_in[3];
    const int* src2 = (const int*)d_in[4], *dst2 = (const int*)d_in[5];
    const int* index = (const int*)d_in[6];
    const float* W1a = (const float*)d_in[7];  const float* b1a = (const float*)d_in[8];
    const float* W2a = (const float*)d_in[9];  const float* b2a = (const float*)d_in[10];
    const float* W1b = (const float*)d_in[11]; const float* b1b = (const float*)d_in[12];
    const float* W2b = (const float*)d_in[13]; const float* b2b = (const float*)d_in[14];

    char* wp = (char*)d_ws;
    auto alloc = [&](size_t bytes) -> char* {
        char* r = wp;
        wp += (bytes + 255) & ~(size_t)255;
        return r;
    };
    float* norms   = (float*)alloc((size_t)4 * NN * 4);
    int*   deg2    = (int*)alloc((size_t)2 * NK * 4);
    int*   rp2     = (int*)alloc((size_t)2 * (NK + 1) * 4);
    int*   cur2    = (int*)alloc((size_t)2 * NK * 4);
    int*   tot     = (int*)alloc((size_t)2 * SAB * 4);
    int*   bcur    = (int*)alloc(48 * 4);       // 32 bcur + 8 tick + pad
    u16*   csr_all = (u16*)alloc((size_t)2 * NE * 2);
    u16*   W1t     = (u16*)alloc((size_t)2 * 512 * 256 * 2);
    u16*   W2t     = (u16*)alloc((size_t)2 * 256 * 128 * 2);
    u16*   Y1      = (u16*)alloc((size_t)2 * NN * 256 * 2);
    u16*   H1      = (u16*)alloc((size_t)2 * NN * 256 * 2);
    u16*   Y2      = (u16*)alloc((size_t)2 * NN * 128 * 2);
    float* H2      = (float*)alloc((size_t)2 * NN * 128 * 4);
    u16*   R       = (u16*)alloc((size_t)NIDX * 256 * 2);
    int*   tick    = bcur + 32;
    // aliases (dead ranges at time of use):
    u32* partial2    = (u32*)Y1;
    u32* partial_out = (u32*)H1;
    u32* ebuf_d      = (u32*)Y2;
    u16* ebuf_s      = (u16*)H2;

    hipMemsetAsync(bcur, 0, 48 * 4, stream);
    partition_kernel<<<dim3(PGX + CVB, 2), 256, 0, stream>>>(
        src1, dst1, src2, dst2, bcur, ebuf_d, ebuf_s, W1a, W1b, W2a, W2b, W1t, W2t);
    bhist_kernel<<<dim3(8 * HCH, 4), 256, 0, stream>>>(ebuf_d, ebuf_s, bcur, partial2, partial_out);
    reduce_hist_kernel<<<(2 * NN + 255) / 256, 256, 0, stream>>>(partial2, partial_out, deg2, norms);
    scanA_kernel<<<dim3(SAB, 2), 1024, 0, stream>>>(deg2, rp2, tot);
    scanC_kernel<<<dim3((NK / 4 + 255) / 256, 2), 256, 0, stream>>>(rp2, cur2, tot);

    // Y1 = (raw @ W1) * ns[row]  (both encoders)  ||  XCD-pinned scatter (ticketed)
    gemm1scat_kernel<<<dim3(MT + SCX, 2, 2), 256, 0, stream>>>(
        raw0, raw1, W1t, Y1, norms, ebuf_d, bcur, tick, cur2, csr_all);
    // H1 = relu(nd * agg(Y1) + b1), both encs; z lower-tri filled alongside
    agg_kernel<256, true, true, true><<<dim3(ZHB + AGB, 2), 256, 0, stream>>>(
        Y1, rp2, csr_all, norms, b1a, b1b, H1, (float*)d_out);
    // Y2 = (H1 @ W2) * ns[row]
    gemm2_kernel<<<dim3(MT, 1, 2), 256, 0, stream>>>(H1, W2t, Y2, norms);
    // H2 = nd * agg(Y2) + b2, f32, both encs
    agg_kernel<128, false, false, false><<<dim3(AGB, 2), 256, 0, stream>>>(
        Y2, rp2, csr_all, norms, b2a, b2b, H2, nullptr);

    // R = [ (c1n+c2n)/2 , (c1n-c2n)/(2*sqrt(3)) ]  (8192 x 256, bf16)
    build_r_kernel<<<NIDX / 4, 256, 0, stream>>>(H2, H2 + (size_t)NN * 128, index, R);
    // z = triu(R @ R^T): upper-tri tiles only (lower filled during agg1)
    zgemm_kernel<<<dim3(ZUB, 1, 1), 256, 0, stream>>>(R, (float*)d_out);
}

// Round 17
// 527.640 us; speedup vs baseline: 1.6607x; 1.1827x over previous
//
#include <hip/hip_runtime.h>
#include <hip/hip_bf16.h>

using u16 = unsigned short;
using u32 = unsigned int;

typedef __attribute__((ext_vector_type(8))) short short8;
typedef __attribute__((ext_vector_type(4))) float f32x4;

__device__ __forceinline__ u16 f2bf_u16(float f) {
    __hip_bfloat16 h = __float2bfloat16(f);
    return __builtin_bit_cast(u16, h);
}
__device__ __forceinline__ float bfu(u32 u) { return __uint_as_float(u << 16); }

static constexpr int NN = 50000;
static constexpr int NE = 1600000;
static constexpr int NIDX = 8192;
static constexpr int NRANGE = 8;
static constexpr int RN = NN / NRANGE;
static constexpr int HCH = 16;
static constexpr int NK = NN * NRANGE;
static constexpr int SAB = (NK + 4095) / 4096;
static constexpr int CAPB = 262144;
static constexpr int PEB = 8192;
static constexpr int PGX = (NE + PEB - 1) / PEB;  // 196
static constexpr int CVB = 640;               // convw blocks per enc-slice
static constexpr int PSTG = 1536;
static constexpr int ZLB = 64 * 63 / 2;       // 2016 lower-tri z tiles
static constexpr int ZHB = ZLB / 2;           // 1008 fill tiles per enc-row of agg1
static constexpr int ZUB = 64 * 65 / 2;       // 2080 upper-tri z tiles
static constexpr int AGB = NN / 4;            // 12500 node-groups per enc
static constexpr int MT = (NN + 127) / 128;   // 391 row tiles
static constexpr int SCX = 256;               // scatter x-extension of gemm1 grid

// ---------------- partition (+ fused convw) ----------------

__global__ __launch_bounds__(256)
void partition_kernel(const int* __restrict__ s1, const int* __restrict__ d1,
                      const int* __restrict__ s2, const int* __restrict__ d2,
                      int* __restrict__ bcur, u32* __restrict__ ebuf_d, u16* __restrict__ ebuf_s,
                      const float* __restrict__ W1a, const float* __restrict__ W1b,
                      const float* __restrict__ W2a, const float* __restrict__ W2b,
                      u16* __restrict__ W1t, u16* __restrict__ W2t) {
    if (blockIdx.x >= PGX) {
        int o = (blockIdx.x - PGX) + CVB * blockIdx.y;
        int idx = o * 256 + threadIdx.x;
        if (idx < 131072) {
            int k = idx >> 8, n = idx & 255;
            W1t[(size_t)n * 512 + k] = f2bf_u16(W1a[idx]);
        } else if (idx < 262144) {
            int j = idx - 131072;
            int k = j >> 8, n = j & 255;
            W1t[(size_t)131072 + (size_t)n * 512 + k] = f2bf_u16(W1b[j]);
        } else if (idx < 294912) {
            int j = idx - 262144;
            int k = j >> 7, n = j & 127;
            W2t[(size_t)n * 256 + k] = f2bf_u16(W2a[j]);
        } else if (idx < 327680) {
            int j = idx - 294912;
            int k = j >> 7, n = j & 127;
            W2t[(size_t)32768 + (size_t)n * 256 + k] = f2bf_u16(W2b[j]);
        }
        return;
    }
    __shared__ u32 stage_d[8][PSTG];
    __shared__ u16 stage_s[8][PSTG];
    __shared__ int cnt_d[8], cnt_s[8], base_d[8], base_s[8];
    int enc = blockIdx.y;
    const int* s = enc ? s2 : s1;
    const int* d = enc ? d2 : d1;
    if (threadIdx.x < 8) { cnt_d[threadIdx.x] = 0; cnt_s[threadIdx.x] = 0; }
    __syncthreads();
    int* bc_d = bcur + enc * 16;
    int* bc_s = bcur + enc * 16 + 8;
    u32* bd = ebuf_d + (size_t)enc * 8 * CAPB;
    u16* bs = ebuf_s + (size_t)enc * 8 * CAPB;
    int e0 = blockIdx.x * PEB;
    int e1 = min(e0 + PEB, NE);
    for (int e = e0 + threadIdx.x * 4; e < e1; e += 1024) {
        int4 sv = *(const int4*)(s + e);
        int4 dv = *(const int4*)(d + e);
        #pragma unroll
        for (int j = 0; j < 4; ++j) {
            int src = j == 0 ? sv.x : j == 1 ? sv.y : j == 2 ? sv.z : sv.w;
            int dst = j == 0 ? dv.x : j == 1 ? dv.y : j == 2 ? dv.z : dv.w;
            int rd = dst / RN;
            u32 entry = (u32)src | ((u32)(dst - rd * RN) << 16);
            int slot = atomicAdd(&cnt_d[rd], 1);
            if (slot < PSTG) stage_d[rd][slot] = entry;
            else { int gp = atomicAdd(&bc_d[rd], 1); bd[(size_t)rd * CAPB + gp] = entry; }
            int rs = src / RN;
            int slot2 = atomicAdd(&cnt_s[rs], 1);
            if (slot2 < PSTG) stage_s[rs][slot2] = (u16)(src - rs * RN);
            else { int gp = atomicAdd(&bc_s[rs], 1); bs[(size_t)rs * CAPB + gp] = (u16)(src - rs * RN); }
        }
    }
    __syncthreads();
    if (threadIdx.x < 8) {
        int b = threadIdx.x;
        base_d[b] = atomicAdd(&bc_d[b], min(cnt_d[b], PSTG));
        base_s[b] = atomicAdd(&bc_s[b], min(cnt_s[b], PSTG));
    }
    __syncthreads();
    #pragma unroll
    for (int b = 0; b < 8; ++b) {
        int nb = min(cnt_d[b], PSTG);
        for (int i = threadIdx.x; i < nb; i += 256)
            bd[(size_t)b * CAPB + base_d[b] + i] = stage_d[b][i];
        int ns = min(cnt_s[b], PSTG);
        for (int i = threadIdx.x; i < ns; i += 256)
            bs[(size_t)b * CAPB + base_s[b] + i] = stage_s[b][i];
    }
}

// ---------------- bucket hist ----------------

__global__ __launch_bounds__(256)
void bhist_kernel(const u32* __restrict__ ebuf_d, const u16* __restrict__ ebuf_s,
                  const int* __restrict__ bcur,
                  u32* __restrict__ partial2, u32* __restrict__ partial_out) {
    __shared__ u32 sh[RN * 2];
    int stripe = blockIdx.x & 7, chunk = blockIdx.x >> 3;
    int enc = blockIdx.y & 1, type = blockIdx.y >> 1;
    if (type == 0) {
        for (int i = threadIdx.x; i < RN * 2; i += 256) sh[i] = 0;
        __syncthreads();
        int size = bcur[enc * 16 + stripe];
        int cs = (size + HCH - 1) / HCH;
        int lo = chunk * cs, hi = min(lo + cs, size);
        const u32* b = ebuf_d + ((size_t)enc * 8 + stripe) * CAPB;
        for (int i = lo + threadIdx.x; i < hi; i += 256) {
            u32 e = b[i];
            u32 idx = (e >> 16) * 8 + (e & 0xffffu) / RN;
            atomicAdd(&sh[idx >> 2], 1u << ((idx & 3) * 8));
        }
        __syncthreads();
        u32* p2 = partial2 + ((size_t)enc * HCH + chunk) * (NN * 2) + stripe * (RN * 2);
        for (int i = threadIdx.x; i < RN * 2; i += 256) p2[i] = sh[i];
    } else {
        for (int i = threadIdx.x; i < RN / 2; i += 256) sh[i] = 0;
        __syncthreads();
        int size = bcur[enc * 16 + 8 + stripe];
        int cs = (size + HCH - 1) / HCH;
        int lo = chunk * cs, hi = min(lo + cs, size);
        const u16* b = ebuf_s + ((size_t)enc * 8 + stripe) * CAPB;
        for (int i = lo + threadIdx.x; i < hi; i += 256) {
            u32 sl = b[i];
            atomicAdd(&sh[sl >> 1], 1u << ((sl & 1) * 16));
        }
        __syncthreads();
        u32* po = partial_out + ((size_t)enc * HCH + chunk) * (NN / 2) + stripe * (RN / 2);
        for (int i = threadIdx.x; i < RN / 2; i += 256) po[i] = sh[i];
    }
}

__global__ void reduce_hist_kernel(const u32* __restrict__ partial2,
                                   const u32* __restrict__ partial_out,
                                   int* __restrict__ deg2, float* __restrict__ norms) {
    int i = blockIdx.x * blockDim.x + threadIdx.x;
    if (i >= 2 * NN) return;
    int enc = i / NN;
    int dst = i - enc * NN;
    int cnt[8];
    #pragma unroll
    for (int r = 0; r < 8; ++r) cnt[r] = 0;
    for (int c = 0; c < HCH; ++c) {
        const u32* p = partial2 + ((size_t)enc * HCH + c) * (NN * 2) + dst * 2;
        u32 w0 = p[0], w1 = p[1];
        cnt[0] += w0 & 0xff; cnt[1] += (w0 >> 8) & 0xff; cnt[2] += (w0 >> 16) & 0xff; cnt[3] += w0 >> 24;
        cnt[4] += w1 & 0xff; cnt[5] += (w1 >> 8) & 0xff; cnt[6] += (w1 >> 16) & 0xff; cnt[7] += w1 >> 24;
    }
    int* dp = deg2 + (size_t)enc * NK + dst * 8;
    int din = 0;
    #pragma unroll
    for (int r = 0; r < 8; ++r) { dp[r] = cnt[r]; din += cnt[r]; }
    norms[(enc * 2 + 1) * NN + dst] = rsqrtf(fmaxf((float)din, 1.f));
    int dout = 0;
    for (int c = 0; c < HCH; ++c) {
        u32 w = partial_out[((size_t)enc * HCH + c) * (NN / 2) + (dst >> 1)];
        dout += (w >> ((dst & 1) * 16)) & 0xffff;
    }
    norms[(enc * 2 + 0) * NN + dst] = rsqrtf(fmaxf((float)dout, 1.f));
}

// ---------------- 2-phase scan ----------------

__global__ __launch_bounds__(1024)
void scanA_kernel(const int* __restrict__ deg2, int* __restrict__ rp2_all, int* __restrict__ tot) {
    int enc = blockIdx.y;
    const int* deg = deg2 + (size_t)enc * NK;
    int* rp = rp2_all + (size_t)enc * (NK + 1);
    __shared__ int wsum[16];
    int t = threadIdx.x, lane = t & 63, wid = t >> 6;
    int i0 = blockIdx.x * 4096 + t * 4;
    int4 v = make_int4(0, 0, 0, 0);
    bool in = (i0 + 3 < NK);
    if (in) v = *(const int4*)(deg + i0);
    int s = v.x + v.y + v.z + v.w;
    int x = s;
    #pragma unroll
    for (int d = 1; d < 64; d <<= 1) {
        int y = __shfl_up(x, d, 64);
        if (lane >= d) x += y;
    }
    if (lane == 63) wsum[wid] = x;
    __syncthreads();
    if (t == 0) {
        int run = 0;
        #pragma unroll
        for (int w = 0; w < 16; ++w) { int q = wsum[w]; wsum[w] = run; run += q; }
        tot[enc * SAB + blockIdx.x] = run;
    }
    __syncthreads();
    if (in) {
        int excl = wsum[wid] + x - s;
        rp[i0] = excl;
        rp[i0 + 1] = excl + v.x;
        rp[i0 + 2] = excl + v.x + v.y;
        rp[i0 + 3] = excl + v.x + v.y + v.z;
    }
}

__global__ __launch_bounds__(256)
void scanC_kernel(int* __restrict__ rp2_all, int* __restrict__ cur2_all, const int* __restrict__ tot) {
    int enc = blockIdx.y;
    int* rp = rp2_all + (size_t)enc * (NK + 1);
    int* cur = cur2_all + (size_t)enc * NK;
    int nA = blockIdx.x >> 2;
    int part = 0;
    for (int i = threadIdx.x; i < nA; i += 256) part += tot[enc * SAB + i];
    #pragma unroll
    for (int d = 1; d < 64; d <<= 1) part += __shfl_xor(part, d, 64);
    __shared__ int red[4];
    __shared__ int soff;
    int lane = threadIdx.x & 63, wv = threadIdx.x >> 6;
    if (lane == 0) red[wv] = part;
    __syncthreads();
    if (threadIdx.x == 0) soff = red[0] + red[1] + red[2] + red[3];
    __syncthreads();
    int off = soff;
    int idx = (blockIdx.x * 256 + threadIdx.x) * 4;
    if (idx < NK) {
        int4 v = *(const int4*)(rp + idx);
        v.x += off; v.y += off; v.z += off; v.w += off;
        *(int4*)(rp + idx) = v;
        *(int4*)(cur + idx) = v;
    }
    if (blockIdx.x == 0 && threadIdx.x == 0) rp[NK] = NE;
}

// ---------------- scatter body ----------------

__device__ __forceinline__ void scatter_body(const u32* __restrict__ ebuf_d,
                                             const int* __restrict__ bcur,
                                             int* __restrict__ cur2_all, u16* __restrict__ csr_all,
                                             int stripe, int chunk, int enc) {
    int size = bcur[enc * 16 + stripe];
    int cs = (size + 63) / 64;
    int lo = chunk * cs, hi = min(lo + cs, size);
    const u32* b = ebuf_d + ((size_t)enc * 8 + stripe) * CAPB;
    int* cursor = cur2_all + (size_t)enc * NK;
    u16* csr = csr_all + (size_t)enc * NE;
    int base = stripe * RN;
    for (int i = lo + threadIdx.x; i < hi; i += 256) {
        u32 e = b[i];
        int src = e & 0xffff;
        int dst = base + (int)(e >> 16);
        int key = dst * 8 + src / RN;
        int pos = atomicAdd(&cursor[key], 1);
        csr[pos] = (u16)src;
    }
}

// ---------------- MFMA GEMM device body ----------------

template<bool A_F32, bool OUT_BF16, bool TRIANG, bool SCALE>
__device__ __forceinline__ void gemm_device(const void* __restrict__ A_, const u16* __restrict__ Bt,
                                            void* __restrict__ C_, const float* __restrict__ rowscale,
                                            int M, int N, int K, int it, int jt, u16* smem) {
    int t = threadIdx.x;
    int brow = it * 128, bcol = jt * 128;
    float* Cf = (float*)C_;
    u16* As = smem;
    u16* Bs = smem + 128 * 40;
    int lane = t & 63, wv = t >> 6;
    int wr = wv >> 1, wc = wv & 1;
    f32x4 acc[4][4];
    #pragma unroll
    for (int m = 0; m < 4; ++m)
        #pragma unroll
        for (int n = 0; n < 4; ++n) acc[m][n] = f32x4{0.f, 0.f, 0.f, 0.f};

    float4 a_f0[4], a_f1[4];
    uint4  a_h0[2], a_h1[2];
    uint4  b_h0[2], b_h1[2];

#define LOADT(S, kk) do {                                                          \
    if constexpr (A_F32) {                                                         \
        const float* A = (const float*)A_;                                         \
        _Pragma("unroll")                                                          \
        for (int p = 0; p < 4; ++p) {                                              \
            int r = p * 32 + (t >> 3), c = (t & 7) * 4;                            \
            int gr = brow + r;                                                     \
            a_f##S[p] = make_float4(0.f, 0.f, 0.f, 0.f);                           \
            if (gr < M) a_f##S[p] = *(const float4*)(A + (size_t)gr * K + (kk) + c); \
        }                                                                          \
    } else {                                                                       \
        const u16* A = (const u16*)A_;                                             \
        _Pragma("unroll")                                                          \
        for (int p = 0; p < 2; ++p) {                                              \
            int r = p * 64 + (t >> 2), c = (t & 3) * 8;                            \
            int gr = brow + r;                                                     \
            a_h##S[p] = make_uint4(0u, 0u, 0u, 0u);                                \
            if (gr < M) a_h##S[p] = *(const uint4*)(A + (size_t)gr * K + (kk) + c); \
        }                                                                          \
    }                                                                              \
    _Pragma("unroll")                                                              \
    for (int p = 0; p < 2; ++p) {                                                  \
        int r = p * 64 + (t >> 2), c = (t & 3) * 8;                                \
        int gn = bcol + r;                                                         \
        b_h##S[p] = make_uint4(0u, 0u, 0u, 0u);                                    \
        if (gn < N) b_h##S[p] = *(const uint4*)(Bt + (size_t)gn * K + (kk) + c);   \
    }                                                                              \
} while (0)

#define STORET(S) do {                                                             \
    if constexpr (A_F32) {                                                         \
        _Pragma("unroll")                                                          \
        for (int p = 0; p < 4; ++p) {                                              \
            int r = p * 32 + (t >> 3), c = (t & 7) * 4;                            \
            u32 lo = (u32)f2bf_u16(a_f##S[p].x) | ((u32)f2bf_u16(a_f##S[p].y) << 16); \
            u32 hi = (u32)f2bf_u16(a_f##S[p].z) | ((u32)f2bf_u16(a_f##S[p].w) << 16); \
            *(uint2*)&As[r * 40 + c] = make_uint2(lo, hi);                         \
        }                                                                          \
    } else {                                                                       \
        _Pragma("unroll")                                                          \
        for (int p = 0; p < 2; ++p) {                                              \
            int r = p * 64 + (t >> 2), c = (t & 3) * 8;                            \
            *(uint4*)&As[r * 40 + c] = a_h##S[p];                                  \
        }                                                                          \
    }                                                                              \
    _Pragma("unroll")                                                              \
    for (int p = 0; p < 2; ++p) {                                                  \
        int r = p * 64 + (t >> 2), c = (t & 3) * 8;                                \
        *(uint4*)&Bs[r * 40 + c] = b_h##S[p];                                      \
    }                                                                              \
} while (0)

    auto compute = [&]() {
        int kg = (lane >> 4) * 8;
        short8 av[4], bv[4];
        #pragma unroll
        for (int m = 0; m < 4; ++m)
            av[m] = *(const short8*)&As[(wr * 64 + m * 16 + (lane & 15)) * 40 + kg];
        #pragma unroll
        for (int n = 0; n < 4; ++n)
            bv[n] = *(const short8*)&Bs[(wc * 64 + n * 16 + (lane & 15)) * 40 + kg];
        #pragma unroll
        for (int m = 0; m < 4; ++m)
            #pragma unroll
            for (int n = 0; n < 4; ++n)
                acc[m][n] = __builtin_amdgcn_mfma_f32_16x16x32_bf16(av[m], bv[n], acc[m][n], 0, 0, 0);
    };

    LOADT(0, 0);
    LOADT(1, 32);
    for (int k0 = 0; k0 < K; k0 += 64) {
        STORET(0);
        __syncthreads();
        if (k0 + 64 < K) LOADT(0, k0 + 64);
        compute();
        __syncthreads();
        STORET(1);
        __syncthreads();
        if (k0 + 96 < K) LOADT(1, k0 + 96);
        compute();
        __syncthreads();
    }
#undef LOADT
#undef STORET

    const int lane15 = lane & 15, lanehi = lane >> 4;
    if (OUT_BF16) {
        u16* stg = smem + wv * 1024;
        #pragma unroll
        for (int m = 0; m < 4; ++m) {
            #pragma unroll
            for (int n = 0; n < 4; ++n)
                #pragma unroll
                for (int r = 0; r < 4; ++r) {
                    float v = acc[m][n][r];
                    if (SCALE) v *= rowscale[brow + wr * 64 + m * 16 + lanehi * 4 + r];
                    stg[(lanehi * 4 + r) * 64 + n * 16 + lane15] = f2bf_u16(v);
                }
            #pragma unroll
            for (int pass = 0; pass < 2; ++pass) {
                int lr = pass * 8 + (lane >> 3);
                int grow = brow + wr * 64 + m * 16 + lr;
                uint4 w = *(uint4*)&stg[lr * 64 + (lane & 7) * 8];
                if (grow < M)
                    *(uint4*)((u16*)C_ + (size_t)grow * N + bcol + wc * 64 + (lane & 7) * 8) = w;
            }
        }
    } else {
        float* stg = (float*)smem + wv * 1024;
        #pragma unroll
        for (int m = 0; m < 4; ++m) {
            #pragma unroll
            for (int n = 0; n < 4; ++n)
                #pragma unroll
                for (int r = 0; r < 4; ++r) {
                    int row = brow + wr * 64 + m * 16 + lanehi * 4 + r;
                    int col = bcol + wc * 64 + n * 16 + lane15;
                    float v = acc[m][n][r];
                    if (SCALE) v *= rowscale[row];
                    if (TRIANG && col < row) v = 0.f;
                    stg[(lanehi * 4 + r) * 64 + n * 16 + lane15] = v;
                }
            #pragma unroll
            for (int pass = 0; pass < 4; ++pass) {
                int lr = pass * 4 + lanehi;
                int grow = brow + wr * 64 + m * 16 + lr;
                f32x4 w = *(f32x4*)&stg[lr * 64 + lane15 * 4];
                if (grow < M) {
                    float* dp = Cf + (size_t)grow * N + bcol + wc * 64 + lane15 * 4;
                    if (TRIANG) __builtin_nontemporal_store(w, (f32x4*)dp);
                    else *(f32x4*)dp = w;
                }
            }
        }
    }
}

// gemm1 fused with scatter
__global__ __launch_bounds__(256)
void gemm1scat_kernel(const float* __restrict__ raw0, const float* __restrict__ raw1,
                      const u16* __restrict__ W1t, u16* __restrict__ Y1,
                      const float* __restrict__ norms,
                      const u32* __restrict__ ebuf_d, const int* __restrict__ bcur,
                      int* __restrict__ tick, int* __restrict__ cur2, u16* __restrict__ csr_all) {
    if (blockIdx.x >= MT) {
        u32 lin = blockIdx.x + gridDim.x * (blockIdx.y + gridDim.y * blockIdx.z);
        int stripe = lin & 7;
        __shared__ int tsh;
        if (threadIdx.x == 0) tsh = atomicAdd(&tick[stripe], 1);
        __syncthreads();
        int tkt = tsh;
        scatter_body(ebuf_d, bcur, cur2, csr_all, stripe, tkt & 63, tkt >> 6);
        return;
    }
    __shared__ alignas(16) u16 smem[128 * 40 * 2];
    int enc = blockIdx.z;
    gemm_device<true, true, false, true>(
        enc ? raw1 : raw0, W1t + (size_t)enc * 512 * 256,
        Y1 + (size_t)enc * NN * 256, norms + (size_t)2 * enc * NN,
        NN, 256, 512, blockIdx.x, blockIdx.y, smem);
}

// gemm2 (dual-enc)
__global__ __launch_bounds__(256)
void gemm2_kernel(const u16* __restrict__ H1, const u16* __restrict__ W2t,
                  u16* __restrict__ Y2, const float* __restrict__ norms) {
    __shared__ alignas(16) u16 smem[128 * 40 * 2];
    int enc = blockIdx.z;
    gemm_device<false, true, false, true>(
        H1 + (size_t)enc * NN * 256, W2t + (size_t)enc * 256 * 128,
        Y2 + (size_t)enc * NN * 128, norms + (size_t)2 * enc * NN,
        NN, 128, 256, blockIdx.x, 0, smem);
}

// z = triu(R @ R^T): 1D upper-tri grid
__global__ __launch_bounds__(256)
void zgemm_kernel(const u16* __restrict__ R, float* __restrict__ out) {
    int b = blockIdx.x;
    int i = (int)((129.0f - sqrtf(129.f * 129.f - 8.f * b)) * 0.5f);
    while ((i + 1) * (129 - (i + 1)) / 2 <= b) ++i;
    while (i * (129 - i) / 2 > b) --i;
    int it = i;
    int jt = i + (b - i * (129 - i) / 2);
    __shared__ alignas(16) u16 smem[128 * 40 * 2];
    gemm_device<false, false, true, false>(R, R, out, nullptr, NIDX, NIDX, 256, it, jt, smem);
}

// ---------------- agg1: row-major, dual-enc (grid.y = enc), + z lower fill ----------------

template<int F, bool RELU, bool OUT_BF16, bool ZFILL>
__global__ __launch_bounds__(256)
void agg_kernel(const u16* __restrict__ Yall, const int* __restrict__ rp2_all,
                const u16* __restrict__ csr_all, const float* __restrict__ norms,
                const float* __restrict__ bias0, const float* __restrict__ bias1,
                void* __restrict__ out_all, float* __restrict__ zout) {
    constexpr int VPL = F / 64;
    int enc = blockIdx.y;
    int bid = blockIdx.x;
    if (ZFILL) {
        if (bid < ZHB) {
            int b = enc * ZHB + bid;
            float fit = (sqrtf(8.f * b + 1.f) + 1.f) * 0.5f;
            int it = (int)fit;
            if (it * (it - 1) / 2 > b) --it;
            else if ((it + 1) * it / 2 <= b) ++it;
            int jt = b - it * (it - 1) / 2;
            int brow = it * 128, bcol = jt * 128;
            f32x4 z = {0.f, 0.f, 0.f, 0.f};
            #pragma unroll
            for (int pq = 0; pq < 16; ++pq) {
                int idx = pq * 256 + threadIdx.x;
                int r = idx >> 5, c4 = idx & 31;
                __builtin_nontemporal_store(z, (f32x4*)(zout + (size_t)(brow + r) * NIDX + bcol + c4 * 4));
            }
            return;
        }
        bid -= ZHB;
    }
    const u16* Y = Yall + (size_t)enc * NN * F;
    const int* rp2 = rp2_all + (size_t)enc * (NK + 1);
    const u16* csr = csr_all + (size_t)enc * NE;
    const float* nd = norms + (size_t)(2 * enc + 1) * NN;
    const float* bias = enc ? bias1 : bias0;
    int lane = threadIdx.x & 63;
    int node = bid * 4 + (threadIdx.x >> 6);
    int e0 = rp2[node * 8], e1 = rp2[node * 8 + 8];
    float acc[VPL];
    #pragma unroll
    for (int j = 0; j < VPL; ++j) acc[j] = 0.f;
    const int off = lane * VPL;

    int e = e0;
    for (; e < e1 && (e & 7) != 0; ++e) {
        int s = csr[e];
        uint2 d = *(const uint2*)(Y + (size_t)s * F + off);
        acc[0] += bfu(d.x & 0xffffu); acc[1] += bfu(d.x >> 16);
        acc[2] += bfu(d.y & 0xffffu); acc[3] += bfu(d.y >> 16);
    }
    for (; e + 16 <= e1; e += 16) {
        uint4 ia = *(const uint4*)(csr + e);
        uint4 ib = *(const uint4*)(csr + e + 8);
        int s0 = ia.x & 0xffff, s1 = ia.x >> 16, s2 = ia.y & 0xffff, s3 = ia.y >> 16;
        int s4 = ia.z & 0xffff, s5 = ia.z >> 16, s6 = ia.w & 0xffff, s7 = ia.w >> 16;
        int s8 = ib.x & 0xffff, s9 = ib.x >> 16, sa = ib.y & 0xffff, sb = ib.y >> 16;
        int sc = ib.z & 0xffff, sd = ib.z >> 16, se = ib.w & 0xffff, sf = ib.w >> 16;
        uint2 d0 = *(const uint2*)(Y + (size_t)s0 * F + off);
        uint2 d1 = *(const uint2*)(Y + (size_t)s1 * F + off);
        uint2 d2 = *(const uint2*)(Y + (size_t)s2 * F + off);
        uint2 d3 = *(const uint2*)(Y + (size_t)s3 * F + off);
        uint2 d4 = *(const uint2*)(Y + (size_t)s4 * F + off);
        uint2 d5 = *(const uint2*)(Y + (size_t)s5 * F + off);
        uint2 d6 = *(const uint2*)(Y + (size_t)s6 * F + off);
        uint2 d7 = *(const uint2*)(Y + (size_t)s7 * F + off);
        uint2 d8 = *(const uint2*)(Y + (size_t)s8 * F + off);
        uint2 d9 = *(const uint2*)(Y + (size_t)s9 * F + off);
        uint2 da = *(const uint2*)(Y + (size_t)sa * F + off);
        uint2 db = *(const uint2*)(Y + (size_t)sb * F + off);
        uint2 dc = *(const uint2*)(Y + (size_t)sc * F + off);
        uint2 dd = *(const uint2*)(Y + (size_t)sd * F + off);
        uint2 de = *(const uint2*)(Y + (size_t)se * F + off);
        uint2 df = *(const uint2*)(Y + (size_t)sf * F + off);
        acc[0] += bfu(d0.x & 0xffffu); acc[1] += bfu(d0.x >> 16); acc[2] += bfu(d0.y & 0xffffu); acc[3] += bfu(d0.y >> 16);
        acc[0] += bfu(d1.x & 0xffffu); acc[1] += bfu(d1.x >> 16); acc[2] += bfu(d1.y & 0xffffu); acc[3] += bfu(d1.y >> 16);
        acc[0] += bfu(d2.x & 0xffffu); acc[1] += bfu(d2.x >> 16); acc[2] += bfu(d2.y & 0xffffu); acc[3] += bfu(d2.y >> 16);
        acc[0] += bfu(d3.x & 0xffffu); acc[1] += bfu(d3.x >> 16); acc[2] += bfu(d3.y & 0xffffu); acc[3] += bfu(d3.y >> 16);
        acc[0] += bfu(d4.x & 0xffffu); acc[1] += bfu(d4.x >> 16); acc[2] += bfu(d4.y & 0xffffu); acc[3] += bfu(d4.y >> 16);
        acc[0] += bfu(d5.x & 0xffffu); acc[1] += bfu(d5.x >> 16); acc[2] += bfu(d5.y & 0xffffu); acc[3] += bfu(d5.y >> 16);
        acc[0] += bfu(d6.x & 0xffffu); acc[1] += bfu(d6.x >> 16); acc[2] += bfu(d6.y & 0xffffu); acc[3] += bfu(d6.y >> 16);
        acc[0] += bfu(d7.x & 0xffffu); acc[1] += bfu(d7.x >> 16); acc[2] += bfu(d7.y & 0xffffu); acc[3] += bfu(d7.y >> 16);
        acc[0] += bfu(d8.x & 0xffffu); acc[1] += bfu(d8.x >> 16); acc[2] += bfu(d8.y & 0xffffu); acc[3] += bfu(d8.y >> 16);
        acc[0] += bfu(d9.x & 0xffffu); acc[1] += bfu(d9.x >> 16); acc[2] += bfu(d9.y & 0xffffu); acc[3] += bfu(d9.y >> 16);
        acc[0] += bfu(da.x & 0xffffu); acc[1] += bfu(da.x >> 16); acc[2] += bfu(da.y & 0xffffu); acc[3] += bfu(da.y >> 16);
        acc[0] += bfu(db.x & 0xffffu); acc[1] += bfu(db.x >> 16); acc[2] += bfu(db.y & 0xffffu); acc[3] += bfu(db.y >> 16);
        acc[0] += bfu(dc.x & 0xffffu); acc[1] += bfu(dc.x >> 16); acc[2] += bfu(dc.y & 0xffffu); acc[3] += bfu(dc.y >> 16);
        acc[0] += bfu(dd.x & 0xffffu); acc[1] += bfu(dd.x >> 16); acc[2] += bfu(dd.y & 0xffffu); acc[3] += bfu(dd.y >> 16);
        acc[0] += bfu(de.x & 0xffffu); acc[1] += bfu(de.x >> 16); acc[2] += bfu(de.y & 0xffffu); acc[3] += bfu(de.y >> 16);
        acc[0] += bfu(df.x & 0xffffu); acc[1] += bfu(df.x >> 16); acc[2] += bfu(df.y & 0xffffu); acc[3] += bfu(df.y >> 16);
    }
    for (; e + 8 <= e1; e += 8) {
        uint4 iv = *(const uint4*)(csr + e);
        int s0 = iv.x & 0xffff, s1 = iv.x >> 16;
        int s2 = iv.y & 0xffff, s3 = iv.y >> 16;
        int s4 = iv.z & 0xffff, s5 = iv.z >> 16;
        int s6 = iv.w & 0xffff, s7 = iv.w >> 16;
        uint2 d0 = *(const uint2*)(Y + (size_t)s0 * F + off);
        uint2 d1 = *(const uint2*)(Y + (size_t)s1 * F + off);
        uint2 d2 = *(const uint2*)(Y + (size_t)s2 * F + off);
        uint2 d3 = *(const uint2*)(Y + (size_t)s3 * F + off);
        uint2 d4 = *(const uint2*)(Y + (size_t)s4 * F + off);
        uint2 d5 = *(const uint2*)(Y + (size_t)s5 * F + off);
        uint2 d6 = *(const uint2*)(Y + (size_t)s6 * F + off);
        uint2 d7 = *(const uint2*)(Y + (size_t)s7 * F + off);
        acc[0] += bfu(d0.x & 0xffffu); acc[1] += bfu(d0.x >> 16); acc[2] += bfu(d0.y & 0xffffu); acc[3] += bfu(d0.y >> 16);
        acc[0] += bfu(d1.x & 0xffffu); acc[1] += bfu(d1.x >> 16); acc[2] += bfu(d1.y & 0xffffu); acc[3] += bfu(d1.y >> 16);
        acc[0] += bfu(d2.x & 0xffffu); acc[1] += bfu(d2.x >> 16); acc[2] += bfu(d2.y & 0xffffu); acc[3] += bfu(d2.y >> 16);
        acc[0] += bfu(d3.x & 0xffffu); acc[1] += bfu(d3.x >> 16); acc[2] += bfu(d3.y & 0xffffu); acc[3] += bfu(d3.y >> 16);
        acc[0] += bfu(d4.x & 0xffffu); acc[1] += bfu(d4.x >> 16); acc[2] += bfu(d4.y & 0xffffu); acc[3] += bfu(d4.y >> 16);
        acc[0] += bfu(d5.x & 0xffffu); acc[1] += bfu(d5.x >> 16); acc[2] += bfu(d5.y & 0xffffu); acc[3] += bfu(d5.y >> 16);
        acc[0] += bfu(d6.x & 0xffffu); acc[1] += bfu(d6.x >> 16); acc[2] += bfu(d6.y & 0xffffu); acc[3] += bfu(d6.y >> 16);
        acc[0] += bfu(d7.x & 0xffffu); acc[1] += bfu(d7.x >> 16); acc[2] += bfu(d7.y & 0xffffu); acc[3] += bfu(d7.y >> 16);
    }
    for (; e < e1; ++e) {
        int s = csr[e];
        uint2 d = *(const uint2*)(Y + (size_t)s * F + off);
        acc[0] += bfu(d.x & 0xffffu); acc[1] += bfu(d.x >> 16);
        acc[2] += bfu(d.y & 0xffffu); acc[3] += bfu(d.y >> 16);
    }

    float ndv = nd[node];
    #pragma unroll
    for (int j = 0; j < VPL; ++j) {
        float o = acc[j] * ndv + bias[off + j];
        if (RELU) o = fmaxf(o, 0.f);
        ((u16*)out_all)[(size_t)enc * NN * F + (size_t)node * F + off + j] = f2bf_u16(o);
    }
}

// ---------------- fused agg2 + normalize + build R (only the 8192 indexed rows) ----------------
// Wave = 1 position; gathers both encoders' Y2 rows (F=128, u32/lane), applies nd*.+b2,
// L2-normalizes in-register (shfl row reduction), emits R row directly.

__global__ __launch_bounds__(256)
void aggr_kernel(const u16* __restrict__ Y2all, const int* __restrict__ rp2_all,
                 const u16* __restrict__ csr_all, const float* __restrict__ norms,
                 const float* __restrict__ b2a, const float* __restrict__ b2b,
                 const int* __restrict__ index, u16* __restrict__ R) {
    int pos = blockIdx.x * 4 + (threadIdx.x >> 6);
    int lane = threadIdx.x & 63;
    int node = index[pos];
    const int off = lane * 2;
    float cx[2], cy[2];
    #pragma unroll
    for (int enc = 0; enc < 2; ++enc) {
        const u16* Y = Y2all + (size_t)enc * NN * 128;
        const int* rp2 = rp2_all + (size_t)enc * (NK + 1);
        const u16* csr = csr_all + (size_t)enc * NE;
        int e0 = rp2[node * 8], e1 = rp2[node * 8 + 8];
        float a0 = 0.f, a1 = 0.f;
        int e = e0;
        for (; e < e1 && (e & 7) != 0; ++e) {
            int s = csr[e];
            u32 d = *(const u32*)(Y + (size_t)s * 128 + off);
            a0 += bfu(d & 0xffffu); a1 += bfu(d >> 16);
        }
        for (; e + 8 <= e1; e += 8) {
            uint4 iv = *(const uint4*)(csr + e);
            int s0 = iv.x & 0xffff, s1 = iv.x >> 16;
            int s2 = iv.y & 0xffff, s3 = iv.y >> 16;
            int s4 = iv.z & 0xffff, s5 = iv.z >> 16;
            int s6 = iv.w & 0xffff, s7 = iv.w >> 16;
            u32 d0 = *(const u32*)(Y + (size_t)s0 * 128 + off);
            u32 d1 = *(const u32*)(Y + (size_t)s1 * 128 + off);
            u32 d2 = *(const u32*)(Y + (size_t)s2 * 128 + off);
            u32 d3 = *(const u32*)(Y + (size_t)s3 * 128 + off);
            u32 d4 = *(const u32*)(Y + (size_t)s4 * 128 + off);
            u32 d5 = *(const u32*)(Y + (size_t)s5 * 128 + off);
            u32 d6 = *(const u32*)(Y + (size_t)s6 * 128 + off);
            u32 d7 = *(const u32*)(Y + (size_t)s7 * 128 + off);
            a0 += bfu(d0 & 0xffffu); a1 += bfu(d0 >> 16);
            a0 += bfu(d1 & 0xffffu); a1 += bfu(d1 >> 16);
            a0 += bfu(d2 & 0xffffu); a1 += bfu(d2 >> 16);
            a0 += bfu(d3 & 0xffffu); a1 += bfu(d3 >> 16);
            a0 += bfu(d4 & 0xffffu); a1 += bfu(d4 >> 16);
            a0 += bfu(d5 & 0xffffu); a1 += bfu(d5 >> 16);
            a0 += bfu(d6 & 0xffffu); a1 += bfu(d6 >> 16);
            a0 += bfu(d7 & 0xffffu); a1 += bfu(d7 >> 16);
        }
        for (; e < e1; ++e) {
            int s = csr[e];
            u32 d = *(const u32*)(Y + (size_t)s * 128 + off);
            a0 += bfu(d & 0xffffu); a1 += bfu(d >> 16);
        }
        float ndv = norms[(2 * enc + 1) * NN + node];
        const float* bias = enc ? b2b : b2a;
        float o0 = a0 * ndv + bias[off];
        float o1 = a1 * ndv + bias[off + 1];
        float ss = o0 * o0 + o1 * o1;
        #pragma unroll
        for (int dshf = 1; dshf < 64; dshf <<= 1) ss += __shfl_xor(ss, dshf, 64);
        float inv = 1.f / fmaxf(sqrtf(ss), 1e-12f);
        cx[enc] = o0 * inv;
        cy[enc] = o1 * inv;
    }
    const float c2 = 0.5f, c3 = 0.28867513459481287f;  // 1/(2*sqrt(3))
    u16* Rp = R + (size_t)pos * 256;
    u32 w0 = (u32)f2bf_u16((cx[0] + cx[1]) * c2) | ((u32)f2bf_u16((cy[0] + cy[1]) * c2) << 16);
    u32 w1 = (u32)f2bf_u16((cx[0] - cx[1]) * c3) | ((u32)f2bf_u16((cy[0] - cy[1]) * c3) << 16);
    *(u32*)(Rp + off) = w0;
    *(u32*)(Rp + 128 + off) = w1;
}

// ---------------- launch ----------------

extern "C" void kernel_launch(void* const* d_in, const int* in_sizes, int n_in,
                              void* d_out, int out_size, void* d_ws, size_t ws_size,
                              hipStream_t stream) {
    (void)in_sizes; (void)n_in; (void)out_size; (void)ws_size;
    const float* raw0 = (const float*)d_in[0];
    const float* raw1 = (const float*)d_in[1];
    const int* src1 = (const int*)d_in[2], *dst1 = (const int*)d_in[3];
    const int* src2 = (const int*)d_in[4], *dst2 = (const int*)d_in[5];
    const int* index = (const int*)d_in[6];
    const float* W1a = (const float*)d_in[7];  const float* b1a = (const float*)d_in[8];
    const float* W2a = (const float*)d_in[9];  const float* b2a = (const float*)d_in[10];
    const float* W1b = (const float*)d_in[11]; const float* b1b = (const float*)d_in[12];
    const float* W2b = (const float*)d_in[13]; const float* b2b = (const float*)d_in[14];

    char* wp = (char*)d_ws;
    auto alloc = [&](size_t bytes) -> char* {
        char* r = wp;
        wp += (bytes + 255) & ~(size_t)255;
        return r;
    };
    float* norms   = (float*)alloc((size_t)4 * NN * 4);
    int*   deg2    = (int*)alloc((size_t)2 * NK * 4);
    int*   rp2     = (int*)alloc((size_t)2 * (NK + 1) * 4);
    int*   cur2    = (int*)alloc((size_t)2 * NK * 4);
    int*   tot     = (int*)alloc((size_t)2 * SAB * 4);
    int*   bcur    = (int*)alloc(48 * 4);       // 32 bcur + 8 tick + pad
    u16*   csr_all = (u16*)alloc((size_t)2 * NE * 2);
    u16*   W1t     = (u16*)alloc((size_t)2 * 512 * 256 * 2);
    u16*   W2t     = (u16*)alloc((size_t)2 * 256 * 128 * 2);
    u16*   Y1      = (u16*)alloc((size_t)2 * NN * 256 * 2);
    u16*   H1      = (u16*)alloc((size_t)2 * NN * 256 * 2);
    u16*   Y2      = (u16*)alloc((size_t)2 * NN * 128 * 2);
    float* H2      = (float*)alloc((size_t)2 * NN * 128 * 4);   // backing for ebuf_s only
    u16*   R       = (u16*)alloc((size_t)NIDX * 256 * 2);
    int*   tick    = bcur + 32;
    // aliases (dead ranges at time of use):
    u32* partial2    = (u32*)Y1;
    u32* partial_out = (u32*)H1;
    u32* ebuf_d      = (u32*)Y2;
    u16* ebuf_s      = (u16*)H2;

    hipMemsetAsync(bcur, 0, 48 * 4, stream);
    partition_kernel<<<dim3(PGX + CVB, 2), 256, 0, stream>>>(
        src1, dst1, src2, dst2, bcur, ebuf_d, ebuf_s, W1a, W1b, W2a, W2b, W1t, W2t);
    bhist_kernel<<<dim3(8 * HCH, 4), 256, 0, stream>>>(ebuf_d, ebuf_s, bcur, partial2, partial_out);
    reduce_hist_kernel<<<(2 * NN + 255) / 256, 256, 0, stream>>>(partial2, partial_out, deg2, norms);
    scanA_kernel<<<dim3(SAB, 2), 1024, 0, stream>>>(deg2, rp2, tot);
    scanC_kernel<<<dim3((NK / 4 + 255) / 256, 2), 256, 0, stream>>>(rp2, cur2, tot);

    // Y1 = (raw @ W1) * ns[row]  (both encoders)  ||  XCD-pinned scatter (ticketed)
    gemm1scat_kernel<<<dim3(MT + SCX, 2, 2), 256, 0, stream>>>(
        raw0, raw1, W1t, Y1, norms, ebuf_d, bcur, tick, cur2, csr_all);
    // H1 = relu(nd * agg(Y1) + b1), both encs; z lower-tri filled alongside
    agg_kernel<256, true, true, true><<<dim3(ZHB + AGB, 2), 256, 0, stream>>>(
        Y1, rp2, csr_all, norms, b1a, b1b, H1, (float*)d_out);
    // Y2 = (H1 @ W2) * ns[row]
    gemm2_kernel<<<dim3(MT, 1, 2), 256, 0, stream>>>(H1, W2t, Y2, norms);
    // R rows: agg2 (indexed rows only) + normalize + combine, fused
    aggr_kernel<<<NIDX / 4, 256, 0, stream>>>(Y2, rp2, csr_all, norms, b2a, b2b, index, R);
    // z = triu(R @ R^T): upper-tri tiles only (lower filled during agg1)
    zgemm_kernel<<<dim3(ZUB, 1, 1), 256, 0, stream>>>(R, (float*)d_out);
}